// Round 1
// baseline (1253.873 us; speedup 1.0000x reference)
//
#include <hip/hip_runtime.h>
#include <math.h>

#define N_NODES 20000
#define IN_DIM  256
#define OUT_DIM 128
#define S_SECT  8
#define K_BR    9
#define NK      (K_BR*OUT_DIM)   // 1152
#define EP_EDGE 40000

// ---------------------------------------------------------------------------
// Kernel A: P = x @ [W_self | W_sect0..7]  (M=20000, K=256, N=1152)
//   cols 0..127          -> Zbuf[n, 0, :]            (z_self, no norm)
//   cols 128+s*128+d     -> Hbuf[s, n, d] * out_norm[n]
// 64x64 tile, 256 threads, 4x4 register block, BK=16.
// ---------------------------------------------------------------------------
__global__ __launch_bounds__(256) void k_gemm_xw(
    const float* __restrict__ x, const float* __restrict__ Wself,
    const float* __restrict__ Wsect, const float* __restrict__ outn,
    float* __restrict__ Hbuf, float* __restrict__ Zbuf)
{
  __shared__ float As[64][17];   // [m][k], +1 pad
  __shared__ float Bs[16][64];   // [k][n]
  const int t  = threadIdx.x;
  const int n0 = blockIdx.x * 64;
  const int j0 = blockIdx.y * 64;
  const int ty = t >> 4, tx = t & 15;

  // B source base: a 64-wide tile is entirely in W_self or one sector
  const float* Bsrc;
  int sector = -1;
  if (j0 < OUT_DIM) {
    Bsrc = Wself + j0;
  } else {
    sector = (j0 - OUT_DIM) >> 7;
    Bsrc = Wsect + (size_t)sector * (IN_DIM*OUT_DIM) + ((j0 - OUT_DIM) & (OUT_DIM-1));
  }

  float acc[4][4];
  #pragma unroll
  for (int q = 0; q < 4; ++q)
    #pragma unroll
    for (int p = 0; p < 4; ++p) acc[q][p] = 0.f;

  const int lr  = t >> 2;          // A-load row 0..63
  const int lc4 = (t & 3) * 4;     // A-load col*4
  const int bc  = t & 63;          // B-load col
  const int bk0 = t >> 6;          // B-load row base 0..3

  for (int k0 = 0; k0 < IN_DIM; k0 += 16) {
    float4 av = {0.f,0.f,0.f,0.f};
    const int gr = n0 + lr;
    if (gr < N_NODES) av = *(const float4*)(x + (size_t)gr*IN_DIM + k0 + lc4);
    As[lr][lc4+0] = av.x; As[lr][lc4+1] = av.y;
    As[lr][lc4+2] = av.z; As[lr][lc4+3] = av.w;
    #pragma unroll
    for (int q = 0; q < 4; ++q) {
      const int kk = bk0 + 4*q;
      Bs[kk][bc] = Bsrc[(size_t)(k0 + kk)*OUT_DIM + bc];
    }
    __syncthreads();
    #pragma unroll
    for (int kk = 0; kk < 16; ++kk) {
      const float4 b4 = *(const float4*)&Bs[kk][tx*4];
      #pragma unroll
      for (int q = 0; q < 4; ++q) {
        const float a = As[ty*4+q][kk];
        acc[q][0] += a*b4.x; acc[q][1] += a*b4.y;
        acc[q][2] += a*b4.z; acc[q][3] += a*b4.w;
      }
    }
    __syncthreads();
  }

  #pragma unroll
  for (int q = 0; q < 4; ++q) {
    const int gr = n0 + ty*4 + q;
    if (gr >= N_NODES) continue;
    float4 v = {acc[q][0], acc[q][1], acc[q][2], acc[q][3]};
    if (j0 < OUT_DIM) {
      *(float4*)(Zbuf + (size_t)gr*NK + j0 + tx*4) = v;
    } else {
      const float on = outn[gr];
      v.x *= on; v.y *= on; v.z *= on; v.w *= on;
      const int d = ((j0 - OUT_DIM) & (OUT_DIM-1)) + tx*4;
      *(float4*)(Hbuf + ((size_t)sector*N_NODES + gr)*OUT_DIM + d) = v;
    }
  }
}

// ---------------------------------------------------------------------------
// Kernel B: Zbuf[r, 1+s, :] += Hbuf[s, c, :]  for each edge (s,e)
// 32 threads per edge, float4 gather + 4 native f32 atomics.
// ---------------------------------------------------------------------------
__global__ __launch_bounds__(256) void k_agg(
    const float* __restrict__ Hbuf, const int* __restrict__ rows,
    const int* __restrict__ cols, float* __restrict__ Zbuf)
{
  const long long tid = (long long)blockIdx.x * 256 + threadIdx.x;
  const int edge = (int)(tid >> 5);
  if (edge >= S_SECT*EP_EDGE) return;
  const int l = (int)(tid & 31);
  const int s = edge / EP_EDGE;
  const int r = rows[edge];
  const int c = cols[edge];
  const float4 h = *(const float4*)(Hbuf + ((size_t)s*N_NODES + c)*OUT_DIM + l*4);
  float* zp = Zbuf + ((size_t)r*K_BR + 1 + s)*OUT_DIM + l*4;
  unsafeAtomicAdd(zp+0, h.x);
  unsafeAtomicAdd(zp+1, h.y);
  unsafeAtomicAdd(zp+2, h.z);
  unsafeAtomicAdd(zp+3, h.w);
}

// ---------------------------------------------------------------------------
// Kernel C: per-node heter_sen_interaction, 4 nodes per 128-thread block.
//   wave 0 -> zc = z@WC, wave 1 -> zd = z@WD  (acc[node][k][2] register block)
//   Gram -> softmax -> combine -> gate -> output. d == threadIdx.x (0..127).
// ---------------------------------------------------------------------------
__global__ __launch_bounds__(128) void k_interact(
    const float* __restrict__ Zbuf, const float* __restrict__ WC,
    const float* __restrict__ WD, const float* __restrict__ gw,
    const float* __restrict__ gb, const float* __restrict__ inn,
    float* __restrict__ out)
{
  __shared__ __align__(16) float zsT[128][40];        // z transposed: [i][node*9+k]
  __shared__ float zcd[2][4][K_BR*129];               // [mat][node][k*129+d], pad 129
  __shared__ float gs[4][2][K_BR][12];                // Gram -> softmax probs
  __shared__ float redw[2];
  const int t    = threadIdx.x;
  const int wave = t >> 6, lane = t & 63;
  const int n0   = blockIdx.x * 4;

  // phase 0: load z * in_norm, transposed
  for (int idx = t; idx < 4*NK; idx += 128) {
    const int node = idx / NK;
    const int rem  = idx - node*NK;
    const int k = rem >> 7, i = rem & 127;
    zsT[i][node*9+k] = Zbuf[(size_t)(n0+node)*NK + rem] * inn[n0+node];
  }
  __syncthreads();

  // phase 1: zc (wave0) / zd (wave1)
  {
    const float* W = wave ? WD : WC;
    float acc[4][9][2];
    #pragma unroll
    for (int nd = 0; nd < 4; ++nd)
      #pragma unroll
      for (int k = 0; k < 9; ++k) { acc[nd][k][0] = 0.f; acc[nd][k][1] = 0.f; }

    float2 w = *(const float2*)(W + lane*2);   // prefetch i=0
    #pragma unroll 2
    for (int i = 0; i < 128; ++i) {
      float2 wn = {0.f, 0.f};
      if (i < 127) wn = *(const float2*)(W + (size_t)(i+1)*OUT_DIM + lane*2);
      float zv[36];
      #pragma unroll
      for (int c = 0; c < 36; c += 4) {
        const float4 tmp = *(const float4*)&zsT[i][c];
        zv[c] = tmp.x; zv[c+1] = tmp.y; zv[c+2] = tmp.z; zv[c+3] = tmp.w;
      }
      #pragma unroll
      for (int nd = 0; nd < 4; ++nd)
        #pragma unroll
        for (int k = 0; k < 9; ++k) {
          acc[nd][k][0] += zv[nd*9+k] * w.x;
          acc[nd][k][1] += zv[nd*9+k] * w.y;
        }
      w = wn;
    }
    #pragma unroll
    for (int nd = 0; nd < 4; ++nd)
      #pragma unroll
      for (int k = 0; k < 9; ++k) {
        zcd[wave][nd][k*129 + lane*2    ] = acc[nd][k][0];
        zcd[wave][nd][k*129 + lane*2 + 1] = acc[nd][k][1];
      }
  }
  __syncthreads();

  // phase 2: Gram matrices (81 pairs x 2 mats x 4 nodes = 648 dots)
  for (int p = t; p < 648; p += 128) {
    const int node = p / 162;
    const int rem  = p - node*162;
    const int mat  = rem / 81;
    const int kj   = rem - mat*81;
    const int k = kj / 9, j = kj - k*9;
    const float* A = &zcd[mat][node][0];
    float s = 0.f;
    for (int i = 0; i < 128; ++i) s += A[k*129+i] * A[j*129+i];
    gs[node][mat][k][j] = s;
  }
  __syncthreads();

  // phase 3: softmax rows (mat0: com rows; mat1: ds[k,j]=G[k,k]-G[k,j])
  if (t < 72) {
    const int node = t / 18;
    const int rem  = t - node*18;
    const int mat  = rem / 9;
    const int k    = rem - mat*9;
    float v[9];
    if (mat == 0) {
      #pragma unroll
      for (int j = 0; j < 9; ++j) v[j] = gs[node][0][k][j];
    } else {
      const float gkk = gs[node][1][k][k];
      #pragma unroll
      for (int j = 0; j < 9; ++j) v[j] = gkk - gs[node][1][k][j];
    }
    float m = v[0];
    #pragma unroll
    for (int j = 1; j < 9; ++j) m = fmaxf(m, v[j]);
    float sum = 0.f;
    #pragma unroll
    for (int j = 0; j < 9; ++j) { v[j] = expf(v[j] - m); sum += v[j]; }
    const float inv = 1.f / sum;
    #pragma unroll
    for (int j = 0; j < 9; ++j) gs[node][mat][k][j] = v[j] * inv;
  }
  __syncthreads();

  // phase 4: combine + gate + output (thread t owns column d = t)
  const float gbv = gb[0];
  for (int node = 0; node < 4; ++node) {
    float zcj[9], zdj[9];
    #pragma unroll
    for (int j = 0; j < 9; ++j) {
      zcj[j] = zcd[0][node][j*129 + t];
      zdj[j] = zcd[1][node][j*129 + t];
    }
    float zcomK[9], zdisK[9];
    float gp = 0.f;
    #pragma unroll
    for (int k = 0; k < 9; ++k) {
      float zc = 0.f, ad = 0.f;
      #pragma unroll
      for (int j = 0; j < 9; ++j) {
        zc += gs[node][0][k][j] * zcj[j];
        ad += gs[node][1][k][j] * zdj[j];
      }
      zcomK[k] = zc;
      zdisK[k] = zdj[k] - ad;   // z_dis = zd - ad@zd (softmax rows sum to 1)
      gp += zc * gw[k*OUT_DIM + t] + zdisK[k] * gw[NK + k*OUT_DIM + t];
    }
    #pragma unroll
    for (int off = 32; off > 0; off >>= 1) gp += __shfl_down(gp, off, 64);
    if (lane == 0) redw[wave] = gp;
    __syncthreads();
    const float beta = 1.f / (1.f + expf(-(redw[0] + redw[1] + gbv)));
    #pragma unroll
    for (int k = 0; k < 9; ++k)
      out[(size_t)(n0+node)*NK + k*OUT_DIM + t] = beta*zcomK[k] + (1.f-beta)*zdisK[k];
    __syncthreads();   // protect redw before next node
  }
}

// ---------------------------------------------------------------------------
extern "C" void kernel_launch(void* const* d_in, const int* in_sizes, int n_in,
                              void* d_out, int out_size, void* d_ws, size_t ws_size,
                              hipStream_t stream)
{
  const float* x     = (const float*)d_in[0];
  const float* Wself = (const float*)d_in[1];
  const float* Wsect = (const float*)d_in[2];
  const float* WC    = (const float*)d_in[3];
  const float* WD    = (const float*)d_in[4];
  const float* gw    = (const float*)d_in[5];
  const float* gb    = (const float*)d_in[6];
  const float* outn  = (const float*)d_in[7];
  const float* inn   = (const float*)d_in[8];
  const int*   rows  = (const int*)d_in[9];
  const int*   cols  = (const int*)d_in[10];
  float* out = (float*)d_out;

  // workspace: Hbuf [S][N][128] f32 (81.92 MB) | Zbuf [N][9][128] f32 (92.16 MB)
  float* Hbuf = (float*)d_ws;
  float* Zbuf = (float*)((char*)d_ws + (size_t)S_SECT*N_NODES*OUT_DIM*sizeof(float));

  hipMemsetAsync(Zbuf, 0, (size_t)N_NODES*NK*sizeof(float), stream);

  dim3 gA((N_NODES + 63)/64, NK/64);                     // 313 x 18
  k_gemm_xw<<<gA, 256, 0, stream>>>(x, Wself, Wsect, outn, Hbuf, Zbuf);

  const int edgeBlocks = (S_SECT*EP_EDGE*32)/256;        // 40000
  k_agg<<<edgeBlocks, 256, 0, stream>>>(Hbuf, rows, cols, Zbuf);

  k_interact<<<N_NODES/4, 128, 0, stream>>>(Zbuf, WC, WD, gw, gb, inn, out);
}

// Round 2
// 792.318 us; speedup vs baseline: 1.5825x; 1.5825x over previous
//
#include <hip/hip_runtime.h>
#include <math.h>

#define N_NODES 20000
#define IN_DIM  256
#define OUT_DIM 128
#define S_SECT  8
#define K_BR    9
#define NK      (K_BR*OUT_DIM)   // 1152
#define EP_EDGE 40000
#define N_EDGES (S_SECT*EP_EDGE) // 320000
#define N_BINS  (S_SECT*N_NODES) // 160000
#define SCAN_BLOCKS 160          // 1000 elems per block

// ---------------------------------------------------------------------------
// Kernel A: P = x @ [W_self | W_sect0..7]  (M=20000, K=256, N=1152)
//   cols 0..127          -> Zbuf[n, 0, :]            (z_self, no norm)
//   cols 128+s*128+d     -> Hbuf[s, n, d] * out_norm[n]
// 64x64 tile, 256 threads, 4x4 register block, BK=16.
// ---------------------------------------------------------------------------
__global__ __launch_bounds__(256) void k_gemm_xw(
    const float* __restrict__ x, const float* __restrict__ Wself,
    const float* __restrict__ Wsect, const float* __restrict__ outn,
    float* __restrict__ Hbuf, float* __restrict__ Zbuf)
{
  __shared__ float As[64][17];   // [m][k], +1 pad
  __shared__ float Bs[16][64];   // [k][n]
  const int t  = threadIdx.x;
  const int n0 = blockIdx.x * 64;
  const int j0 = blockIdx.y * 64;
  const int ty = t >> 4, tx = t & 15;

  const float* Bsrc;
  int sector = -1;
  if (j0 < OUT_DIM) {
    Bsrc = Wself + j0;
  } else {
    sector = (j0 - OUT_DIM) >> 7;
    Bsrc = Wsect + (size_t)sector * (IN_DIM*OUT_DIM) + ((j0 - OUT_DIM) & (OUT_DIM-1));
  }

  float acc[4][4];
  #pragma unroll
  for (int q = 0; q < 4; ++q)
    #pragma unroll
    for (int p = 0; p < 4; ++p) acc[q][p] = 0.f;

  const int lr  = t >> 2;
  const int lc4 = (t & 3) * 4;
  const int bc  = t & 63;
  const int bk0 = t >> 6;

  for (int k0 = 0; k0 < IN_DIM; k0 += 16) {
    float4 av = {0.f,0.f,0.f,0.f};
    const int gr = n0 + lr;
    if (gr < N_NODES) av = *(const float4*)(x + (size_t)gr*IN_DIM + k0 + lc4);
    As[lr][lc4+0] = av.x; As[lr][lc4+1] = av.y;
    As[lr][lc4+2] = av.z; As[lr][lc4+3] = av.w;
    #pragma unroll
    for (int q = 0; q < 4; ++q) {
      const int kk = bk0 + 4*q;
      Bs[kk][bc] = Bsrc[(size_t)(k0 + kk)*OUT_DIM + bc];
    }
    __syncthreads();
    #pragma unroll
    for (int kk = 0; kk < 16; ++kk) {
      const float4 b4 = *(const float4*)&Bs[kk][tx*4];
      #pragma unroll
      for (int q = 0; q < 4; ++q) {
        const float a = As[ty*4+q][kk];
        acc[q][0] += a*b4.x; acc[q][1] += a*b4.y;
        acc[q][2] += a*b4.z; acc[q][3] += a*b4.w;
      }
    }
    __syncthreads();
  }

  #pragma unroll
  for (int q = 0; q < 4; ++q) {
    const int gr = n0 + ty*4 + q;
    if (gr >= N_NODES) continue;
    float4 v = {acc[q][0], acc[q][1], acc[q][2], acc[q][3]};
    if (j0 < OUT_DIM) {
      *(float4*)(Zbuf + (size_t)gr*NK + j0 + tx*4) = v;
    } else {
      const float on = outn[gr];
      v.x *= on; v.y *= on; v.z *= on; v.w *= on;
      const int d = ((j0 - OUT_DIM) & (OUT_DIM-1)) + tx*4;
      *(float4*)(Hbuf + ((size_t)sector*N_NODES + gr)*OUT_DIM + d) = v;
    }
  }
}

// ---------------------------------------------------------------------------
// CSR build: count -> scan(3 stages) -> scatter
// ---------------------------------------------------------------------------
__global__ __launch_bounds__(256) void k_count(
    const int* __restrict__ rows, int* __restrict__ cnt)
{
  const int id = blockIdx.x * 256 + threadIdx.x;
  if (id >= N_EDGES) return;
  const int s = id / EP_EDGE;
  atomicAdd(&cnt[s * N_NODES + rows[id]], 1);
}

// per-block totals (1000 elems/block)
__global__ __launch_bounds__(256) void k_scan1(
    const int* __restrict__ cnt, int* __restrict__ bsum)
{
  __shared__ int sh[256];
  const int t = threadIdx.x;
  const int base = blockIdx.x * 1000;
  int s = 0;
  if (t < 250) {
    const int i = base + t*4;
    s = cnt[i] + cnt[i+1] + cnt[i+2] + cnt[i+3];
  }
  sh[t] = s; __syncthreads();
  for (int off = 128; off > 0; off >>= 1) {
    if (t < off) sh[t] += sh[t + off];
    __syncthreads();
  }
  if (t == 0) bsum[blockIdx.x] = sh[0];
}

__global__ void k_scan2(const int* __restrict__ bsum, int* __restrict__ boff)
{
  if (threadIdx.x == 0) {
    int acc = 0;
    for (int b = 0; b < SCAN_BLOCKS; ++b) { boff[b] = acc; acc += bsum[b]; }
  }
}

// final exclusive offsets
__global__ __launch_bounds__(256) void k_scan3(
    const int* __restrict__ cnt, const int* __restrict__ boff,
    int* __restrict__ offs)
{
  __shared__ int sh[256];
  const int t = threadIdx.x;
  const int base = blockIdx.x * 1000;
  int v[4] = {0,0,0,0};
  int mySum = 0;
  if (t < 250) {
    const int i = base + t*4;
    v[0]=cnt[i]; v[1]=cnt[i+1]; v[2]=cnt[i+2]; v[3]=cnt[i+3];
    mySum = v[0]+v[1]+v[2]+v[3];
  }
  sh[t] = mySum; __syncthreads();
  // inclusive Hillis-Steele
  for (int off = 1; off < 256; off <<= 1) {
    int add = (t >= off) ? sh[t - off] : 0;
    __syncthreads();
    sh[t] += add;
    __syncthreads();
  }
  if (t < 250) {
    int excl = boff[blockIdx.x] + sh[t] - mySum;
    const int i = base + t*4;
    offs[i]   = excl;           excl += v[0];
    offs[i+1] = excl;           excl += v[1];
    offs[i+2] = excl;           excl += v[2];
    offs[i+3] = excl;
  }
}

__global__ __launch_bounds__(256) void k_scatter(
    const int* __restrict__ rows, const int* __restrict__ cols,
    const int* __restrict__ offs, int* __restrict__ cur,
    int* __restrict__ eCol)
{
  const int id = blockIdx.x * 256 + threadIdx.x;
  if (id >= N_EDGES) return;
  const int s = id / EP_EDGE;
  const int bin = s * N_NODES + rows[id];
  const int pos = offs[bin] + atomicAdd(&cur[bin], 1);
  eCol[pos] = cols[id];
}

// ---------------------------------------------------------------------------
// Kernel B': pull aggregation. One 32-lane group per (s,r) bin; register
// accumulate over the bin's edges; single float4 store. No f32 atomics.
// ---------------------------------------------------------------------------
__global__ __launch_bounds__(256) void k_agg_csr(
    const float* __restrict__ Hbuf, const int* __restrict__ offs,
    const int* __restrict__ cnt, const int* __restrict__ eCol,
    float* __restrict__ Zbuf)
{
  const long long tid = (long long)blockIdx.x * 256 + threadIdx.x;
  const int group = (int)(tid >> 5);
  if (group >= N_BINS) return;
  const int lane = (int)(tid & 31);
  const int s = group / N_NODES;
  const int r = group - s * N_NODES;
  const int start = offs[group];
  const int n = cnt[group];
  float4 acc = {0.f, 0.f, 0.f, 0.f};
  for (int i = 0; i < n; ++i) {
    const int c = eCol[start + i];
    const float4 h = *(const float4*)(Hbuf + ((size_t)s*N_NODES + c)*OUT_DIM + lane*4);
    acc.x += h.x; acc.y += h.y; acc.z += h.z; acc.w += h.w;
  }
  *(float4*)(Zbuf + ((size_t)r*K_BR + 1 + s)*OUT_DIM + lane*4) = acc;
}

// ---------------------------------------------------------------------------
// Kernel C: per-node heter_sen_interaction, 4 nodes per 128-thread block.
// ---------------------------------------------------------------------------
__global__ __launch_bounds__(128) void k_interact(
    const float* __restrict__ Zbuf, const float* __restrict__ WC,
    const float* __restrict__ WD, const float* __restrict__ gw,
    const float* __restrict__ gb, const float* __restrict__ inn,
    float* __restrict__ out)
{
  __shared__ __align__(16) float zsT[128][40];
  __shared__ float zcd[2][4][K_BR*129];
  __shared__ float gs[4][2][K_BR][12];
  __shared__ float redw[2];
  const int t    = threadIdx.x;
  const int wave = t >> 6, lane = t & 63;
  const int n0   = blockIdx.x * 4;

  for (int idx = t; idx < 4*NK; idx += 128) {
    const int node = idx / NK;
    const int rem  = idx - node*NK;
    const int k = rem >> 7, i = rem & 127;
    zsT[i][node*9+k] = Zbuf[(size_t)(n0+node)*NK + rem] * inn[n0+node];
  }
  __syncthreads();

  {
    const float* W = wave ? WD : WC;
    float acc[4][9][2];
    #pragma unroll
    for (int nd = 0; nd < 4; ++nd)
      #pragma unroll
      for (int k = 0; k < 9; ++k) { acc[nd][k][0] = 0.f; acc[nd][k][1] = 0.f; }

    float2 w = *(const float2*)(W + lane*2);
    #pragma unroll 2
    for (int i = 0; i < 128; ++i) {
      float2 wn = {0.f, 0.f};
      if (i < 127) wn = *(const float2*)(W + (size_t)(i+1)*OUT_DIM + lane*2);
      float zv[36];
      #pragma unroll
      for (int c = 0; c < 36; c += 4) {
        const float4 tmp = *(const float4*)&zsT[i][c];
        zv[c] = tmp.x; zv[c+1] = tmp.y; zv[c+2] = tmp.z; zv[c+3] = tmp.w;
      }
      #pragma unroll
      for (int nd = 0; nd < 4; ++nd)
        #pragma unroll
        for (int k = 0; k < 9; ++k) {
          acc[nd][k][0] += zv[nd*9+k] * w.x;
          acc[nd][k][1] += zv[nd*9+k] * w.y;
        }
      w = wn;
    }
    #pragma unroll
    for (int nd = 0; nd < 4; ++nd)
      #pragma unroll
      for (int k = 0; k < 9; ++k) {
        zcd[wave][nd][k*129 + lane*2    ] = acc[nd][k][0];
        zcd[wave][nd][k*129 + lane*2 + 1] = acc[nd][k][1];
      }
  }
  __syncthreads();

  for (int p = t; p < 648; p += 128) {
    const int node = p / 162;
    const int rem  = p - node*162;
    const int mat  = rem / 81;
    const int kj   = rem - mat*81;
    const int k = kj / 9, j = kj - k*9;
    const float* A = &zcd[mat][node][0];
    float s = 0.f;
    for (int i = 0; i < 128; ++i) s += A[k*129+i] * A[j*129+i];
    gs[node][mat][k][j] = s;
  }
  __syncthreads();

  if (t < 72) {
    const int node = t / 18;
    const int rem  = t - node*18;
    const int mat  = rem / 9;
    const int k    = rem - mat*9;
    float v[9];
    if (mat == 0) {
      #pragma unroll
      for (int j = 0; j < 9; ++j) v[j] = gs[node][0][k][j];
    } else {
      const float gkk = gs[node][1][k][k];
      #pragma unroll
      for (int j = 0; j < 9; ++j) v[j] = gkk - gs[node][1][k][j];
    }
    float m = v[0];
    #pragma unroll
    for (int j = 1; j < 9; ++j) m = fmaxf(m, v[j]);
    float sum = 0.f;
    #pragma unroll
    for (int j = 0; j < 9; ++j) { v[j] = expf(v[j] - m); sum += v[j]; }
    const float inv = 1.f / sum;
    #pragma unroll
    for (int j = 0; j < 9; ++j) gs[node][mat][k][j] = v[j] * inv;
  }
  __syncthreads();

  const float gbv = gb[0];
  for (int node = 0; node < 4; ++node) {
    float zcj[9], zdj[9];
    #pragma unroll
    for (int j = 0; j < 9; ++j) {
      zcj[j] = zcd[0][node][j*129 + t];
      zdj[j] = zcd[1][node][j*129 + t];
    }
    float zcomK[9], zdisK[9];
    float gp = 0.f;
    #pragma unroll
    for (int k = 0; k < 9; ++k) {
      float zc = 0.f, ad = 0.f;
      #pragma unroll
      for (int j = 0; j < 9; ++j) {
        zc += gs[node][0][k][j] * zcj[j];
        ad += gs[node][1][k][j] * zdj[j];
      }
      zcomK[k] = zc;
      zdisK[k] = zdj[k] - ad;
      gp += zc * gw[k*OUT_DIM + t] + zdisK[k] * gw[NK + k*OUT_DIM + t];
    }
    #pragma unroll
    for (int off = 32; off > 0; off >>= 1) gp += __shfl_down(gp, off, 64);
    if (lane == 0) redw[wave] = gp;
    __syncthreads();
    const float beta = 1.f / (1.f + expf(-(redw[0] + redw[1] + gbv)));
    #pragma unroll
    for (int k = 0; k < 9; ++k)
      out[(size_t)(n0+node)*NK + k*OUT_DIM + t] = beta*zcomK[k] + (1.f-beta)*zdisK[k];
    __syncthreads();
  }
}

// ---------------------------------------------------------------------------
extern "C" void kernel_launch(void* const* d_in, const int* in_sizes, int n_in,
                              void* d_out, int out_size, void* d_ws, size_t ws_size,
                              hipStream_t stream)
{
  const float* x     = (const float*)d_in[0];
  const float* Wself = (const float*)d_in[1];
  const float* Wsect = (const float*)d_in[2];
  const float* WC    = (const float*)d_in[3];
  const float* WD    = (const float*)d_in[4];
  const float* gw    = (const float*)d_in[5];
  const float* gb    = (const float*)d_in[6];
  const float* outn  = (const float*)d_in[7];
  const float* inn   = (const float*)d_in[8];
  const int*   rows  = (const int*)d_in[9];
  const int*   cols  = (const int*)d_in[10];
  float* out = (float*)d_out;

  // workspace layout (bytes, 256-aligned):
  char* p = (char*)d_ws;
  float* Hbuf = (float*)p;                 p += (size_t)S_SECT*N_NODES*OUT_DIM*4;   // 81.92 MB
  float* Zbuf = (float*)p;                 p += (size_t)N_NODES*NK*4;               // 92.16 MB
  int* cnt    = (int*)p;                   p += (size_t)N_BINS*4;                   // 640 KB
  int* offs   = (int*)p;                   p += (size_t)N_BINS*4;
  int* cur    = (int*)p;                   p += (size_t)N_BINS*4;
  int* bsum   = (int*)p;                   p += 256*4;
  int* boff   = (int*)p;                   p += 256*4;
  int* eCol   = (int*)p;                   p += (size_t)N_EDGES*4;                  // 1.28 MB

  // zero the CSR counters (cnt, then offs/cur are overwritten; cur must be 0)
  hipMemsetAsync(cnt, 0, (size_t)N_BINS*4, stream);
  hipMemsetAsync(cur, 0, (size_t)N_BINS*4, stream);

  dim3 gA((N_NODES + 63)/64, NK/64);
  k_gemm_xw<<<gA, 256, 0, stream>>>(x, Wself, Wsect, outn, Hbuf, Zbuf);

  const int eb = (N_EDGES + 255)/256;
  k_count  <<<eb, 256, 0, stream>>>(rows, cnt);
  k_scan1  <<<SCAN_BLOCKS, 256, 0, stream>>>(cnt, bsum);
  k_scan2  <<<1, 64, 0, stream>>>(bsum, boff);
  k_scan3  <<<SCAN_BLOCKS, 256, 0, stream>>>(cnt, boff, offs);
  k_scatter<<<eb, 256, 0, stream>>>(rows, cols, offs, cur, eCol);

  const int aggBlocks = (N_BINS*32 + 255)/256;   // 20000
  k_agg_csr<<<aggBlocks, 256, 0, stream>>>(Hbuf, offs, cnt, eCol, Zbuf);

  k_interact<<<N_NODES/4, 128, 0, stream>>>(Zbuf, WC, WD, gw, gb, inn, out);
}

// Round 3
// 527.872 us; speedup vs baseline: 2.3753x; 1.5010x over previous
//
#include <hip/hip_runtime.h>
#include <math.h>

#define N_NODES 20000
#define IN_DIM  256
#define OUT_DIM 128
#define S_SECT  8
#define K_BR    9
#define NK      (K_BR*OUT_DIM)   // 1152
#define EP_EDGE 40000
#define N_EDGES (S_SECT*EP_EDGE) // 320000
#define N_BINS  (S_SECT*N_NODES) // 160000
#define SCAN_BLOCKS 160
#define M_ROWS  (N_NODES*K_BR)   // 180000

typedef float v4f __attribute__((ext_vector_type(4)));
typedef short v8s __attribute__((ext_vector_type(8)));

__device__ inline unsigned short f2bf(float f) {
  union { float f; unsigned u; } v; v.f = f;
  unsigned r = v.u + 0x7fff + ((v.u >> 16) & 1);   // RNE
  return (unsigned short)(r >> 16);
}
__device__ inline float bf2f(unsigned short h) {
  union { unsigned u; float f; } v; v.u = ((unsigned)h) << 16;
  return v.f;
}

// ---------------------------------------------------------------------------
// Kernel A: P = x @ [W_self | W_sect0..7]  (fp32 VALU GEMM, unchanged core)
//   cols 0..127     -> Zbuf[n,0,:] * in_norm[n]          (fp32)
//   cols 128+s*128  -> Hbuf[s,n,:] * out_norm[n]         (bf16)
// ---------------------------------------------------------------------------
__global__ __launch_bounds__(256) void k_gemm_xw(
    const float* __restrict__ x, const float* __restrict__ Wself,
    const float* __restrict__ Wsect, const float* __restrict__ outn,
    const float* __restrict__ inn,
    unsigned short* __restrict__ Hbuf, float* __restrict__ Zbuf)
{
  __shared__ float As[64][17];
  __shared__ float Bs[16][64];
  const int t  = threadIdx.x;
  const int n0 = blockIdx.x * 64;
  const int j0 = blockIdx.y * 64;
  const int ty = t >> 4, tx = t & 15;

  const float* Bsrc;
  int sector = -1;
  if (j0 < OUT_DIM) {
    Bsrc = Wself + j0;
  } else {
    sector = (j0 - OUT_DIM) >> 7;
    Bsrc = Wsect + (size_t)sector * (IN_DIM*OUT_DIM) + ((j0 - OUT_DIM) & (OUT_DIM-1));
  }

  float acc[4][4];
  #pragma unroll
  for (int q = 0; q < 4; ++q)
    #pragma unroll
    for (int p = 0; p < 4; ++p) acc[q][p] = 0.f;

  const int lr  = t >> 2;
  const int lc4 = (t & 3) * 4;
  const int bc  = t & 63;
  const int bk0 = t >> 6;

  for (int k0 = 0; k0 < IN_DIM; k0 += 16) {
    float4 av = {0.f,0.f,0.f,0.f};
    const int gr = n0 + lr;
    if (gr < N_NODES) av = *(const float4*)(x + (size_t)gr*IN_DIM + k0 + lc4);
    As[lr][lc4+0] = av.x; As[lr][lc4+1] = av.y;
    As[lr][lc4+2] = av.z; As[lr][lc4+3] = av.w;
    #pragma unroll
    for (int q = 0; q < 4; ++q) {
      const int kk = bk0 + 4*q;
      Bs[kk][bc] = Bsrc[(size_t)(k0 + kk)*OUT_DIM + bc];
    }
    __syncthreads();
    #pragma unroll
    for (int kk = 0; kk < 16; ++kk) {
      const float4 b4 = *(const float4*)&Bs[kk][tx*4];
      #pragma unroll
      for (int q = 0; q < 4; ++q) {
        const float a = As[ty*4+q][kk];
        acc[q][0] += a*b4.x; acc[q][1] += a*b4.y;
        acc[q][2] += a*b4.z; acc[q][3] += a*b4.w;
      }
    }
    __syncthreads();
  }

  #pragma unroll
  for (int q = 0; q < 4; ++q) {
    const int gr = n0 + ty*4 + q;
    if (gr >= N_NODES) continue;
    float4 v = {acc[q][0], acc[q][1], acc[q][2], acc[q][3]};
    if (j0 < OUT_DIM) {
      const float w = inn[gr];
      v.x *= w; v.y *= w; v.z *= w; v.w *= w;
      *(float4*)(Zbuf + (size_t)gr*NK + j0 + tx*4) = v;
    } else {
      const float on = outn[gr];
      ushort4 b;
      b.x = f2bf(v.x*on); b.y = f2bf(v.y*on);
      b.z = f2bf(v.z*on); b.w = f2bf(v.w*on);
      const int d = ((j0 - OUT_DIM) & (OUT_DIM-1)) + tx*4;
      *(ushort4*)(Hbuf + ((size_t)sector*N_NODES + gr)*OUT_DIM + d) = b;
    }
  }
}

// ---------------------------------------------------------------------------
// CSR build: count -> scan(3) -> scatter (unchanged)
// ---------------------------------------------------------------------------
__global__ __launch_bounds__(256) void k_count(
    const int* __restrict__ rows, int* __restrict__ cnt)
{
  const int id = blockIdx.x * 256 + threadIdx.x;
  if (id >= N_EDGES) return;
  const int s = id / EP_EDGE;
  atomicAdd(&cnt[s * N_NODES + rows[id]], 1);
}

__global__ __launch_bounds__(256) void k_scan1(
    const int* __restrict__ cnt, int* __restrict__ bsum)
{
  __shared__ int sh[256];
  const int t = threadIdx.x;
  const int base = blockIdx.x * 1000;
  int s = 0;
  if (t < 250) {
    const int i = base + t*4;
    s = cnt[i] + cnt[i+1] + cnt[i+2] + cnt[i+3];
  }
  sh[t] = s; __syncthreads();
  for (int off = 128; off > 0; off >>= 1) {
    if (t < off) sh[t] += sh[t + off];
    __syncthreads();
  }
  if (t == 0) bsum[blockIdx.x] = sh[0];
}

__global__ void k_scan2(const int* __restrict__ bsum, int* __restrict__ boff)
{
  if (threadIdx.x == 0) {
    int acc = 0;
    for (int b = 0; b < SCAN_BLOCKS; ++b) { boff[b] = acc; acc += bsum[b]; }
  }
}

__global__ __launch_bounds__(256) void k_scan3(
    const int* __restrict__ cnt, const int* __restrict__ boff,
    int* __restrict__ offs)
{
  __shared__ int sh[256];
  const int t = threadIdx.x;
  const int base = blockIdx.x * 1000;
  int v[4] = {0,0,0,0};
  int mySum = 0;
  if (t < 250) {
    const int i = base + t*4;
    v[0]=cnt[i]; v[1]=cnt[i+1]; v[2]=cnt[i+2]; v[3]=cnt[i+3];
    mySum = v[0]+v[1]+v[2]+v[3];
  }
  sh[t] = mySum; __syncthreads();
  for (int off = 1; off < 256; off <<= 1) {
    int add = (t >= off) ? sh[t - off] : 0;
    __syncthreads();
    sh[t] += add;
    __syncthreads();
  }
  if (t < 250) {
    int excl = boff[blockIdx.x] + sh[t] - mySum;
    const int i = base + t*4;
    offs[i]   = excl;           excl += v[0];
    offs[i+1] = excl;           excl += v[1];
    offs[i+2] = excl;           excl += v[2];
    offs[i+3] = excl;
  }
}

__global__ __launch_bounds__(256) void k_scatter(
    const int* __restrict__ rows, const int* __restrict__ cols,
    const int* __restrict__ offs, int* __restrict__ cur,
    int* __restrict__ eCol)
{
  const int id = blockIdx.x * 256 + threadIdx.x;
  if (id >= N_EDGES) return;
  const int s = id / EP_EDGE;
  const int bin = s * N_NODES + rows[id];
  const int pos = offs[bin] + atomicAdd(&cur[bin], 1);
  eCol[pos] = cols[id];
}

// ---------------------------------------------------------------------------
// Kernel B': pull aggregation from bf16 Hbuf; fold in_norm; fp32 store.
// ---------------------------------------------------------------------------
__global__ __launch_bounds__(256) void k_agg_csr(
    const unsigned short* __restrict__ Hbuf, const int* __restrict__ offs,
    const int* __restrict__ cnt, const int* __restrict__ eCol,
    const float* __restrict__ inn, float* __restrict__ Zbuf)
{
  const long long tid = (long long)blockIdx.x * 256 + threadIdx.x;
  const int group = (int)(tid >> 5);
  if (group >= N_BINS) return;
  const int lane = (int)(tid & 31);
  const int s = group / N_NODES;
  const int r = group - s * N_NODES;
  const int start = offs[group];
  const int n = cnt[group];
  float4 acc = {0.f, 0.f, 0.f, 0.f};
  for (int i = 0; i < n; ++i) {
    const int c = eCol[start + i];
    const uint2 h = *(const uint2*)(Hbuf + ((size_t)s*N_NODES + c)*OUT_DIM + lane*4);
    acc.x += bf2f((unsigned short)h.x);
    acc.y += bf2f((unsigned short)(h.x >> 16));
    acc.z += bf2f((unsigned short)h.y);
    acc.w += bf2f((unsigned short)(h.y >> 16));
  }
  const float w = inn[r];
  acc.x *= w; acc.y *= w; acc.z *= w; acc.w *= w;
  *(float4*)(Zbuf + ((size_t)r*K_BR + 1 + s)*OUT_DIM + lane*4) = acc;
}

// ---------------------------------------------------------------------------
// Btg[n][k] = bf16([WC|WD][k][n])   (256 x 128, 64 KB)
// ---------------------------------------------------------------------------
__global__ __launch_bounds__(256) void k_prep_bt(
    const float* __restrict__ WC, const float* __restrict__ WD,
    unsigned short* __restrict__ Btg)
{
  const int id = blockIdx.x * 256 + threadIdx.x;   // 32768
  const int n = id >> 7, k = id & 127;
  const float w = (n < OUT_DIM) ? WC[k*OUT_DIM + n] : WD[k*OUT_DIM + (n - OUT_DIM)];
  Btg[id] = f2bf(w);
}

// ---------------------------------------------------------------------------
// Kernel ZCD: [zc|zd] = Zbuf[180000,128] @ Bt^T  via bf16 MFMA 16x16x32.
// No LDS. Per block: 256 thr / 4 waves; M-tile 128 (wave: 2x16 rows),
// N = 256 full. A direct from global (fp32->bf16), B frags from L2 (Btg).
// Output bf16: ZCD[mat][node][k][d].
// ---------------------------------------------------------------------------
__global__ __launch_bounds__(256, 2) void k_gemm_zcd(
    const float* __restrict__ Zbuf, const unsigned short* __restrict__ Btg,
    unsigned short* __restrict__ ZCD)
{
  const int t = threadIdx.x;
  const int wave = t >> 6, lane = t & 63;
  const int m0 = blockIdx.x * 128 + wave * 32;
  const int mrow = lane & 15, quad = lane >> 4;

  // A fragments: rows m0+rb*16+mrow, full K=128 (4 k-quads of 8)
  v8s afr[2][4];
  #pragma unroll
  for (int rb = 0; rb < 2; ++rb) {
    const int r = m0 + rb*16 + mrow;
    const bool ok = (r < M_ROWS);
    const float* src = Zbuf + (size_t)r*OUT_DIM + quad*8;
    #pragma unroll
    for (int kq = 0; kq < 4; ++kq) {
      float4 a0 = {0.f,0.f,0.f,0.f}, a1 = {0.f,0.f,0.f,0.f};
      if (ok) {
        a0 = *(const float4*)(src + kq*32);
        a1 = *(const float4*)(src + kq*32 + 4);
      }
      v8s f;
      f[0] = (short)f2bf(a0.x); f[1] = (short)f2bf(a0.y);
      f[2] = (short)f2bf(a0.z); f[3] = (short)f2bf(a0.w);
      f[4] = (short)f2bf(a1.x); f[5] = (short)f2bf(a1.y);
      f[6] = (short)f2bf(a1.z); f[7] = (short)f2bf(a1.w);
      afr[rb][kq] = f;
    }
  }

  v4f acc[2][16];
  #pragma unroll
  for (int rb = 0; rb < 2; ++rb)
    #pragma unroll
    for (int j = 0; j < 16; ++j) acc[rb][j] = (v4f){0.f,0.f,0.f,0.f};

  #pragma unroll
  for (int j = 0; j < 16; ++j) {
    const unsigned short* bp = Btg + (size_t)(j*16 + mrow)*128 + quad*8;
    #pragma unroll
    for (int kq = 0; kq < 4; ++kq) {
      const v8s bf = *(const v8s*)(bp + kq*32);
      acc[0][j] = __builtin_amdgcn_mfma_f32_16x16x32_bf16(afr[0][kq], bf, acc[0][j], 0, 0, 0);
      acc[1][j] = __builtin_amdgcn_mfma_f32_16x16x32_bf16(afr[1][kq], bf, acc[1][j], 0, 0, 0);
    }
  }

  // C/D: col = lane&15 (+16j), row = quad*4 + p (+rb*16)
  unsigned short* Zc = ZCD;
  unsigned short* Zd = ZCD + (size_t)N_NODES*NK;
  #pragma unroll
  for (int rb = 0; rb < 2; ++rb)
    #pragma unroll
    for (int p = 0; p < 4; ++p) {
      const int R = m0 + rb*16 + quad*4 + p;
      if (R >= M_ROWS) continue;
      const int node = R / 9, kk = R - node*9;
      const size_t base = (size_t)node*NK + kk*OUT_DIM;
      #pragma unroll
      for (int j = 0; j < 16; ++j) {
        const unsigned short v = f2bf(acc[rb][j][p]);
        if (j < 8) Zc[base + j*16 + mrow] = v;
        else       Zd[base + (j-8)*16 + mrow] = v;
      }
    }
}

// ---------------------------------------------------------------------------
// Kernel C': interaction from precomputed zc/zd. 8 nodes / 256 threads.
// LDS 80.6 KB -> 2 blocks/CU. Gram uses symmetry (720 dots).
// ---------------------------------------------------------------------------
__device__ static const signed char TKd[45] =
 {0,1,1,2,2,2,3,3,3,3,4,4,4,4,4,5,5,5,5,5,5,6,6,6,6,6,6,6,7,7,7,7,7,7,7,7,8,8,8,8,8,8,8,8,8};
__device__ static const signed char TJd[45] =
 {0,0,1,0,1,2,0,1,2,3,0,1,2,3,4,0,1,2,3,4,5,0,1,2,3,4,5,6,0,1,2,3,4,5,6,7,0,1,2,3,4,5,6,7,8};

#define ZP 130   // zcd LDS row pitch (words): 130%32=2 -> k-rows hit distinct banks

__global__ __launch_bounds__(256, 2) void k_interact_lite(
    const unsigned short* __restrict__ ZCD, const float* __restrict__ gw,
    const float* __restrict__ gb, float* __restrict__ out)
{
  __shared__ float zcd[2][8][K_BR*ZP];   // 74880 B
  __shared__ float gs[8][2][K_BR][10];   // 5760 B
  __shared__ float redw[2][2];
  const int t  = threadIdx.x;
  const int n0 = blockIdx.x * 8;

  // phase 0: bf16 -> fp32 into LDS (4 elems per thread-iter, coalesced)
  for (int it = 0; it < 18; ++it) {
    const int i4  = t + it*256;                 // 0..4607
    const int mat = (i4 >= 2304) ? 1 : 0;
    const int rem4 = i4 - mat*2304;
    const int flat = rem4 * 4;                  // node*1152 + k*128 + d
    const int node = flat / NK;
    const int r2   = flat - node*NK;
    const int k = r2 >> 7, d = r2 & 127;
    const uint2 h = *(const uint2*)(ZCD + (size_t)mat*N_NODES*NK + (size_t)(n0+node)*NK + r2);
    float* dst = &zcd[mat][node][k*ZP + d];
    ((float2*)dst)[0] = (float2){bf2f((unsigned short)h.x), bf2f((unsigned short)(h.x>>16))};
    ((float2*)dst)[1] = (float2){bf2f((unsigned short)h.y), bf2f((unsigned short)(h.y>>16))};
  }
  __syncthreads();

  // phase 1: Gram (symmetric; 8 nodes x 2 mats x 45 pairs)
  for (int p = t; p < 720; p += 256) {
    const int node = p / 90;
    const int rem  = p - node*90;
    const int mat  = (rem >= 45) ? 1 : 0;
    const int pair = rem - mat*45;
    const int k = TKd[pair], j = TJd[pair];
    const float* A = &zcd[mat][node][0];
    float s = 0.f;
    #pragma unroll 4
    for (int i = 0; i < 128; ++i) s += A[k*ZP+i] * A[j*ZP+i];
    gs[node][mat][k][j] = s;
    gs[node][mat][j][k] = s;
  }
  __syncthreads();

  // phase 2: softmax rows
  if (t < 144) {
    const int node = t / 18;
    const int rem  = t - node*18;
    const int mat  = (rem >= 9) ? 1 : 0;
    const int k    = rem - mat*9;
    float v[9];
    if (mat == 0) {
      #pragma unroll
      for (int j = 0; j < 9; ++j) v[j] = gs[node][0][k][j];
    } else {
      const float gkk = gs[node][1][k][k];
      #pragma unroll
      for (int j = 0; j < 9; ++j) v[j] = gkk - gs[node][1][k][j];
    }
    float m = v[0];
    #pragma unroll
    for (int j = 1; j < 9; ++j) m = fmaxf(m, v[j]);
    float sum = 0.f;
    #pragma unroll
    for (int j = 0; j < 9; ++j) { v[j] = expf(v[j] - m); sum += v[j]; }
    const float inv = 1.f / sum;
    #pragma unroll
    for (int j = 0; j < 9; ++j) gs[node][mat][k][j] = v[j] * inv;
  }
  __syncthreads();

  // phase 3: combine + gate + output. 128-thread half-group per 4 nodes.
  const int half = t >> 7;          // 0/1 -> nodes half*4 .. half*4+3
  const int d    = t & 127;
  const int wh   = (t >> 6) & 1;    // wave-half within group
  const int lane = t & 63;
  const float gbv = gb[0];
  for (int nn = 0; nn < 4; ++nn) {
    const int node = half*4 + nn;
    float zcj[9], zdj[9];
    #pragma unroll
    for (int j = 0; j < 9; ++j) {
      zcj[j] = zcd[0][node][j*ZP + d];
      zdj[j] = zcd[1][node][j*ZP + d];
    }
    float zcomK[9], zdisK[9];
    float gp = 0.f;
    #pragma unroll
    for (int k = 0; k < 9; ++k) {
      float zc = 0.f, ad = 0.f;
      #pragma unroll
      for (int j = 0; j < 9; ++j) {
        zc += gs[node][0][k][j] * zcj[j];
        ad += gs[node][1][k][j] * zdj[j];
      }
      zcomK[k] = zc;
      zdisK[k] = zdj[k] - ad;
      gp += zc * gw[k*OUT_DIM + d] + zdisK[k] * gw[NK + k*OUT_DIM + d];
    }
    #pragma unroll
    for (int off = 32; off > 0; off >>= 1) gp += __shfl_down(gp, off, 64);
    if (lane == 0) redw[half][wh] = gp;
    __syncthreads();
    const float beta = 1.f / (1.f + expf(-(redw[half][0] + redw[half][1] + gbv)));
    #pragma unroll
    for (int k = 0; k < 9; ++k)
      out[(size_t)(n0+node)*NK + k*OUT_DIM + d] = beta*zcomK[k] + (1.f-beta)*zdisK[k];
    __syncthreads();
  }
}

// ---------------------------------------------------------------------------
extern "C" void kernel_launch(void* const* d_in, const int* in_sizes, int n_in,
                              void* d_out, int out_size, void* d_ws, size_t ws_size,
                              hipStream_t stream)
{
  const float* x     = (const float*)d_in[0];
  const float* Wself = (const float*)d_in[1];
  const float* Wsect = (const float*)d_in[2];
  const float* WC    = (const float*)d_in[3];
  const float* WD    = (const float*)d_in[4];
  const float* gw    = (const float*)d_in[5];
  const float* gb    = (const float*)d_in[6];
  const float* outn  = (const float*)d_in[7];
  const float* inn   = (const float*)d_in[8];
  const int*   rows  = (const int*)d_in[9];
  const int*   cols  = (const int*)d_in[10];
  float* out = (float*)d_out;

  // workspace: Hbuf bf16 40.96 MB | Zbuf f32 92.16 | ZCD bf16 92.16 | CSR ~3.9
  char* p = (char*)d_ws;
  unsigned short* Hbuf = (unsigned short*)p; p += (size_t)S_SECT*N_NODES*OUT_DIM*2;
  float* Zbuf = (float*)p;                   p += (size_t)M_ROWS*OUT_DIM*4;
  unsigned short* ZCD = (unsigned short*)p;  p += (size_t)2*N_NODES*NK*2;
  int* cnt    = (int*)p;                     p += (size_t)N_BINS*4;
  int* offs   = (int*)p;                     p += (size_t)N_BINS*4;
  int* cur    = (int*)p;                     p += (size_t)N_BINS*4;
  int* bsum   = (int*)p;                     p += 256*4;
  int* boff   = (int*)p;                     p += 256*4;
  int* eCol   = (int*)p;                     p += (size_t)N_EDGES*4;
  unsigned short* Btg = (unsigned short*)p;  p += 256*128*2;

  hipMemsetAsync(cnt, 0, (size_t)N_BINS*4, stream);
  hipMemsetAsync(cur, 0, (size_t)N_BINS*4, stream);

  dim3 gA((N_NODES + 63)/64, NK/64);
  k_gemm_xw<<<gA, 256, 0, stream>>>(x, Wself, Wsect, outn, inn, Hbuf, Zbuf);

  const int eb = (N_EDGES + 255)/256;
  k_count  <<<eb, 256, 0, stream>>>(rows, cnt);
  k_scan1  <<<SCAN_BLOCKS, 256, 0, stream>>>(cnt, bsum);
  k_scan2  <<<1, 64, 0, stream>>>(bsum, boff);
  k_scan3  <<<SCAN_BLOCKS, 256, 0, stream>>>(cnt, boff, offs);
  k_scatter<<<eb, 256, 0, stream>>>(rows, cols, offs, cur, eCol);

  const int aggBlocks = (N_BINS*32 + 255)/256;
  k_agg_csr<<<aggBlocks, 256, 0, stream>>>(Hbuf, offs, cnt, eCol, inn, Zbuf);

  k_prep_bt<<<128, 256, 0, stream>>>(WC, WD, Btg);
  k_gemm_zcd<<<(M_ROWS + 127)/128, 256, 0, stream>>>(Zbuf, Btg, ZCD);

  k_interact_lite<<<N_NODES/8, 256, 0, stream>>>(ZCD, gw, gb, out);
}

// Round 4
// 503.115 us; speedup vs baseline: 2.4922x; 1.0492x over previous
//
#include <hip/hip_runtime.h>
#include <math.h>

#define N_NODES 20000
#define M_PAD   20032            // nodes padded to 64
#define IN_DIM  256
#define OUT_DIM 128
#define S_SECT  8
#define K_BR    9
#define NK      (K_BR*OUT_DIM)   // 1152
#define EP_EDGE 40000
#define N_EDGES (S_SECT*EP_EDGE) // 320000
#define N_BINS  (S_SECT*N_NODES) // 160000
#define SCAN_BLOCKS 160
#define M_ROWS  (N_NODES*K_BR)   // 180000

typedef float v4f __attribute__((ext_vector_type(4)));
typedef short v8s __attribute__((ext_vector_type(8)));

__device__ inline unsigned short f2bf(float f) {
  union { float f; unsigned u; } v; v.f = f;
  unsigned r = v.u + 0x7fff + ((v.u >> 16) & 1);   // RNE
  return (unsigned short)(r >> 16);
}
__device__ inline float bf2f(unsigned short h) {
  union { unsigned u; float f; } v; v.u = ((unsigned)h) << 16;
  return v.f;
}

// ---------------------------------------------------------------------------
// prep: xb[M_PAD][256] = bf16(x), pad rows zeroed
// ---------------------------------------------------------------------------
__global__ __launch_bounds__(256) void k_prep_x(
    const float* __restrict__ x, unsigned short* __restrict__ xb)
{
  const int id = blockIdx.x * 256 + threadIdx.x;      // float4 index
  if (id >= M_PAD*IN_DIM/4) return;
  ushort4 b = {0,0,0,0};
  if (id < N_NODES*IN_DIM/4) {
    const float4 v = *(const float4*)(x + (size_t)id*4);
    b.x = f2bf(v.x); b.y = f2bf(v.y); b.z = f2bf(v.z); b.w = f2bf(v.w);
  }
  *(ushort4*)(xb + (size_t)id*4) = b;
}

// prep: Wtg[j][k] = bf16(Wcat[k][j]), j = 0..1151 (self | sect0..7)
__global__ __launch_bounds__(256) void k_prep_wt(
    const float* __restrict__ Wself, const float* __restrict__ Wsect,
    unsigned short* __restrict__ Wtg)
{
  const int id = blockIdx.x * 256 + threadIdx.x;      // 294912
  if (id >= NK*IN_DIM) return;
  const int j = id >> 8, k = id & 255;
  float w;
  if (j < OUT_DIM) w = Wself[(size_t)k*OUT_DIM + j];
  else {
    const int s = (j - OUT_DIM) >> 7, c = (j - OUT_DIM) & 127;
    w = Wsect[(size_t)s*(IN_DIM*OUT_DIM) + (size_t)k*OUT_DIM + c];
  }
  Wtg[id] = f2bf(w);
}

// ---------------------------------------------------------------------------
// Kernel A (MFMA): P = xb @ Wtg^T  (M=20032, K=256, N=1152 in 3 chunks of 384)
//   col j<128  -> Zbuf[n,0,j] * in_norm[n]   (fp32)
//   col j>=128 -> Hbuf[s,n,d] * out_norm[n]  (bf16)
// Block: 256 thr / 4 waves, wave = 16 rows. No LDS; B frags from L2.
// ---------------------------------------------------------------------------
__global__ __launch_bounds__(256, 2) void k_gemm_xw_mfma(
    const unsigned short* __restrict__ xb, const unsigned short* __restrict__ Wtg,
    const float* __restrict__ outn, const float* __restrict__ inn,
    unsigned short* __restrict__ Hbuf, float* __restrict__ Zbuf)
{
  const int t = threadIdx.x;
  const int wave = t >> 6, lane = t & 63;
  const int mrow = lane & 15, quad = lane >> 4;
  const int m0 = (blockIdx.x * 4 + wave) * 16;
  const int jbase = blockIdx.y * 384;

  // A fragments: row m0+mrow, k-chunk kq covers K [kq*32, kq*32+32)
  v8s afr[8];
  const unsigned short* asrc = xb + (size_t)(m0 + mrow)*IN_DIM + quad*8;
  #pragma unroll
  for (int kq = 0; kq < 8; ++kq) afr[kq] = *(const v8s*)(asrc + kq*32);

  v4f acc[24];
  #pragma unroll
  for (int jt = 0; jt < 24; ++jt) acc[jt] = (v4f){0.f,0.f,0.f,0.f};

  const unsigned short* wb = Wtg + (size_t)(jbase + mrow)*IN_DIM + quad*8;
  #pragma unroll
  for (int kq = 0; kq < 8; ++kq) {
    #pragma unroll
    for (int jt = 0; jt < 24; ++jt) {
      const v8s bf = *(const v8s*)(wb + jt*16*IN_DIM + kq*32);
      acc[jt] = __builtin_amdgcn_mfma_f32_16x16x32_bf16(afr[kq], bf, acc[jt], 0, 0, 0);
    }
  }

  // C/D: row = m0 + quad*4 + p, col = jbase + jt*16 + mrow
  #pragma unroll
  for (int p = 0; p < 4; ++p) {
    const int R = m0 + quad*4 + p;
    if (R >= N_NODES) continue;
    const float iw = inn[R], ow = outn[R];
    #pragma unroll
    for (int jt = 0; jt < 24; ++jt) {
      const int j = jbase + jt*16 + mrow;
      const float v = acc[jt][p];
      if (j < OUT_DIM) {
        Zbuf[(size_t)R*NK + j] = v * iw;
      } else {
        const int s = (j - OUT_DIM) >> 7, d = (j - OUT_DIM) & 127;
        Hbuf[((size_t)s*N_NODES + R)*OUT_DIM + d] = f2bf(v * ow);
      }
    }
  }
}

// ---------------------------------------------------------------------------
// CSR build: count -> scan(3) -> scatter
// ---------------------------------------------------------------------------
__global__ __launch_bounds__(256) void k_count(
    const int* __restrict__ rows, int* __restrict__ cnt)
{
  const int id = blockIdx.x * 256 + threadIdx.x;
  if (id >= N_EDGES) return;
  const int s = id / EP_EDGE;
  atomicAdd(&cnt[s * N_NODES + rows[id]], 1);
}

__global__ __launch_bounds__(256) void k_scan1(
    const int* __restrict__ cnt, int* __restrict__ bsum)
{
  __shared__ int sh[256];
  const int t = threadIdx.x;
  const int base = blockIdx.x * 1000;
  int s = 0;
  if (t < 250) {
    const int i = base + t*4;
    s = cnt[i] + cnt[i+1] + cnt[i+2] + cnt[i+3];
  }
  sh[t] = s; __syncthreads();
  for (int off = 128; off > 0; off >>= 1) {
    if (t < off) sh[t] += sh[t + off];
    __syncthreads();
  }
  if (t == 0) bsum[blockIdx.x] = sh[0];
}

__global__ void k_scan2(const int* __restrict__ bsum, int* __restrict__ boff)
{
  if (threadIdx.x == 0) {
    int acc = 0;
    for (int b = 0; b < SCAN_BLOCKS; ++b) { boff[b] = acc; acc += bsum[b]; }
  }
}

__global__ __launch_bounds__(256) void k_scan3(
    const int* __restrict__ cnt, const int* __restrict__ boff,
    int* __restrict__ offs)
{
  __shared__ int sh[256];
  const int t = threadIdx.x;
  const int base = blockIdx.x * 1000;
  int v[4] = {0,0,0,0};
  int mySum = 0;
  if (t < 250) {
    const int i = base + t*4;
    v[0]=cnt[i]; v[1]=cnt[i+1]; v[2]=cnt[i+2]; v[3]=cnt[i+3];
    mySum = v[0]+v[1]+v[2]+v[3];
  }
  sh[t] = mySum; __syncthreads();
  for (int off = 1; off < 256; off <<= 1) {
    int add = (t >= off) ? sh[t - off] : 0;
    __syncthreads();
    sh[t] += add;
    __syncthreads();
  }
  if (t < 250) {
    int excl = boff[blockIdx.x] + sh[t] - mySum;
    const int i = base + t*4;
    offs[i]   = excl;           excl += v[0];
    offs[i+1] = excl;           excl += v[1];
    offs[i+2] = excl;           excl += v[2];
    offs[i+3] = excl;
  }
}

__global__ __launch_bounds__(256) void k_scatter(
    const int* __restrict__ rows, const int* __restrict__ cols,
    const int* __restrict__ offs, int* __restrict__ cur,
    int* __restrict__ eCol)
{
  const int id = blockIdx.x * 256 + threadIdx.x;
  if (id >= N_EDGES) return;
  const int s = id / EP_EDGE;
  const int bin = s * N_NODES + rows[id];
  const int pos = offs[bin] + atomicAdd(&cur[bin], 1);
  eCol[pos] = cols[id];
}

// ---------------------------------------------------------------------------
// Kernel B': pull aggregation from bf16 Hbuf; fold in_norm; fp32 store.
// ---------------------------------------------------------------------------
__global__ __launch_bounds__(256) void k_agg_csr(
    const unsigned short* __restrict__ Hbuf, const int* __restrict__ offs,
    const int* __restrict__ cnt, const int* __restrict__ eCol,
    const float* __restrict__ inn, float* __restrict__ Zbuf)
{
  const long long tid = (long long)blockIdx.x * 256 + threadIdx.x;
  const int group = (int)(tid >> 5);
  if (group >= N_BINS) return;
  const int lane = (int)(tid & 31);
  const int s = group / N_NODES;
  const int r = group - s * N_NODES;
  const int start = offs[group];
  const int n = cnt[group];
  float4 acc = {0.f, 0.f, 0.f, 0.f};
  for (int i = 0; i < n; ++i) {
    const int c = eCol[start + i];
    const uint2 h = *(const uint2*)(Hbuf + ((size_t)s*N_NODES + c)*OUT_DIM + lane*4);
    acc.x += bf2f((unsigned short)h.x);
    acc.y += bf2f((unsigned short)(h.x >> 16));
    acc.z += bf2f((unsigned short)h.y);
    acc.w += bf2f((unsigned short)(h.y >> 16));
  }
  const float w = inn[r];
  acc.x *= w; acc.y *= w; acc.z *= w; acc.w *= w;
  *(float4*)(Zbuf + ((size_t)r*K_BR + 1 + s)*OUT_DIM + lane*4) = acc;
}

// ---------------------------------------------------------------------------
// Btg[n][k] = bf16([WC|WD][k][n])   (256 x 128, 64 KB)
// ---------------------------------------------------------------------------
__global__ __launch_bounds__(256) void k_prep_bt(
    const float* __restrict__ WC, const float* __restrict__ WD,
    unsigned short* __restrict__ Btg)
{
  const int id = blockIdx.x * 256 + threadIdx.x;   // 32768
  const int n = id >> 7, k = id & 127;
  const float w = (n < OUT_DIM) ? WC[k*OUT_DIM + n] : WD[k*OUT_DIM + (n - OUT_DIM)];
  Btg[id] = f2bf(w);
}

// ---------------------------------------------------------------------------
// Kernel ZCD: [zc|zd] = Zbuf[180000,128] @ Bt^T  via bf16 MFMA 16x16x32.
// ---------------------------------------------------------------------------
__global__ __launch_bounds__(256, 2) void k_gemm_zcd(
    const float* __restrict__ Zbuf, const unsigned short* __restrict__ Btg,
    unsigned short* __restrict__ ZCD)
{
  const int t = threadIdx.x;
  const int wave = t >> 6, lane = t & 63;
  const int m0 = blockIdx.x * 128 + wave * 32;
  const int mrow = lane & 15, quad = lane >> 4;

  v8s afr[2][4];
  #pragma unroll
  for (int rb = 0; rb < 2; ++rb) {
    const int r = m0 + rb*16 + mrow;
    const bool ok = (r < M_ROWS);
    const float* src = Zbuf + (size_t)r*OUT_DIM + quad*8;
    #pragma unroll
    for (int kq = 0; kq < 4; ++kq) {
      float4 a0 = {0.f,0.f,0.f,0.f}, a1 = {0.f,0.f,0.f,0.f};
      if (ok) {
        a0 = *(const float4*)(src + kq*32);
        a1 = *(const float4*)(src + kq*32 + 4);
      }
      v8s f;
      f[0] = (short)f2bf(a0.x); f[1] = (short)f2bf(a0.y);
      f[2] = (short)f2bf(a0.z); f[3] = (short)f2bf(a0.w);
      f[4] = (short)f2bf(a1.x); f[5] = (short)f2bf(a1.y);
      f[6] = (short)f2bf(a1.z); f[7] = (short)f2bf(a1.w);
      afr[rb][kq] = f;
    }
  }

  v4f acc[2][16];
  #pragma unroll
  for (int rb = 0; rb < 2; ++rb)
    #pragma unroll
    for (int j = 0; j < 16; ++j) acc[rb][j] = (v4f){0.f,0.f,0.f,0.f};

  #pragma unroll
  for (int j = 0; j < 16; ++j) {
    const unsigned short* bp = Btg + (size_t)(j*16 + mrow)*128 + quad*8;
    #pragma unroll
    for (int kq = 0; kq < 4; ++kq) {
      const v8s bf = *(const v8s*)(bp + kq*32);
      acc[0][j] = __builtin_amdgcn_mfma_f32_16x16x32_bf16(afr[0][kq], bf, acc[0][j], 0, 0, 0);
      acc[1][j] = __builtin_amdgcn_mfma_f32_16x16x32_bf16(afr[1][kq], bf, acc[1][j], 0, 0, 0);
    }
  }

  unsigned short* Zc = ZCD;
  unsigned short* Zd = ZCD + (size_t)N_NODES*NK;
  #pragma unroll
  for (int rb = 0; rb < 2; ++rb)
    #pragma unroll
    for (int p = 0; p < 4; ++p) {
      const int R = m0 + rb*16 + quad*4 + p;
      if (R >= M_ROWS) continue;
      const int node = R / 9, kk = R - node*9;
      const size_t base = (size_t)node*NK + kk*OUT_DIM;
      #pragma unroll
      for (int j = 0; j < 16; ++j) {
        const unsigned short v = f2bf(acc[rb][j][p]);
        if (j < 8) Zc[base + j*16 + mrow] = v;
        else       Zd[base + (j-8)*16 + mrow] = v;
      }
    }
}

// ---------------------------------------------------------------------------
// Kernel C': interaction from precomputed zc/zd. 8 nodes / 256 threads.
// ---------------------------------------------------------------------------
__device__ static const signed char TKd[45] =
 {0,1,1,2,2,2,3,3,3,3,4,4,4,4,4,5,5,5,5,5,5,6,6,6,6,6,6,6,7,7,7,7,7,7,7,7,8,8,8,8,8,8,8,8,8};
__device__ static const signed char TJd[45] =
 {0,0,1,0,1,2,0,1,2,3,0,1,2,3,4,0,1,2,3,4,5,0,1,2,3,4,5,6,0,1,2,3,4,5,6,7,0,1,2,3,4,5,6,7,8};

#define ZP 130

__global__ __launch_bounds__(256, 2) void k_interact_lite(
    const unsigned short* __restrict__ ZCD, const float* __restrict__ gw,
    const float* __restrict__ gb, float* __restrict__ out)
{
  __shared__ float zcd[2][8][K_BR*ZP];
  __shared__ float gs[8][2][K_BR][10];
  __shared__ float redw[2][2];
  const int t  = threadIdx.x;
  const int n0 = blockIdx.x * 8;

  for (int it = 0; it < 18; ++it) {
    const int i4  = t + it*256;
    const int mat = (i4 >= 2304) ? 1 : 0;
    const int rem4 = i4 - mat*2304;
    const int flat = rem4 * 4;
    const int node = flat / NK;
    const int r2   = flat - node*NK;
    const int k = r2 >> 7, d = r2 & 127;
    const uint2 h = *(const uint2*)(ZCD + (size_t)mat*N_NODES*NK + (size_t)(n0+node)*NK + r2);
    float* dst = &zcd[mat][node][k*ZP + d];
    ((float2*)dst)[0] = (float2){bf2f((unsigned short)h.x), bf2f((unsigned short)(h.x>>16))};
    ((float2*)dst)[1] = (float2){bf2f((unsigned short)h.y), bf2f((unsigned short)(h.y>>16))};
  }
  __syncthreads();

  for (int p = t; p < 720; p += 256) {
    const int node = p / 90;
    const int rem  = p - node*90;
    const int mat  = (rem >= 45) ? 1 : 0;
    const int pair = rem - mat*45;
    const int k = TKd[pair], j = TJd[pair];
    const float* A = &zcd[mat][node][0];
    float s = 0.f;
    #pragma unroll 4
    for (int i = 0; i < 128; ++i) s += A[k*ZP+i] * A[j*ZP+i];
    gs[node][mat][k][j] = s;
    gs[node][mat][j][k] = s;
  }
  __syncthreads();

  if (t < 144) {
    const int node = t / 18;
    const int rem  = t - node*18;
    const int mat  = (rem >= 9) ? 1 : 0;
    const int k    = rem - mat*9;
    float v[9];
    if (mat == 0) {
      #pragma unroll
      for (int j = 0; j < 9; ++j) v[j] = gs[node][0][k][j];
    } else {
      const float gkk = gs[node][1][k][k];
      #pragma unroll
      for (int j = 0; j < 9; ++j) v[j] = gkk - gs[node][1][k][j];
    }
    float m = v[0];
    #pragma unroll
    for (int j = 1; j < 9; ++j) m = fmaxf(m, v[j]);
    float sum = 0.f;
    #pragma unroll
    for (int j = 0; j < 9; ++j) { v[j] = expf(v[j] - m); sum += v[j]; }
    const float inv = 1.f / sum;
    #pragma unroll
    for (int j = 0; j < 9; ++j) gs[node][mat][k][j] = v[j] * inv;
  }
  __syncthreads();

  const int half = t >> 7;
  const int d    = t & 127;
  const int wh   = (t >> 6) & 1;
  const int lane = t & 63;
  const float gbv = gb[0];
  for (int nn = 0; nn < 4; ++nn) {
    const int node = half*4 + nn;
    float zcj[9], zdj[9];
    #pragma unroll
    for (int j = 0; j < 9; ++j) {
      zcj[j] = zcd[0][node][j*ZP + d];
      zdj[j] = zcd[1][node][j*ZP + d];
    }
    float zcomK[9], zdisK[9];
    float gp = 0.f;
    #pragma unroll
    for (int k = 0; k < 9; ++k) {
      float zc = 0.f, ad = 0.f;
      #pragma unroll
      for (int j = 0; j < 9; ++j) {
        zc += gs[node][0][k][j] * zcj[j];
        ad += gs[node][1][k][j] * zdj[j];
      }
      zcomK[k] = zc;
      zdisK[k] = zdj[k] - ad;
      gp += zc * gw[k*OUT_DIM + d] + zdisK[k] * gw[NK + k*OUT_DIM + d];
    }
    #pragma unroll
    for (int off = 32; off > 0; off >>= 1) gp += __shfl_down(gp, off, 64);
    if (lane == 0) redw[half][wh] = gp;
    __syncthreads();
    const float beta = 1.f / (1.f + expf(-(redw[half][0] + redw[half][1] + gbv)));
    #pragma unroll
    for (int k = 0; k < 9; ++k)
      out[(size_t)(n0+node)*NK + k*OUT_DIM + d] = beta*zcomK[k] + (1.f-beta)*zdisK[k];
    __syncthreads();
  }
}

// ---------------------------------------------------------------------------
extern "C" void kernel_launch(void* const* d_in, const int* in_sizes, int n_in,
                              void* d_out, int out_size, void* d_ws, size_t ws_size,
                              hipStream_t stream)
{
  const float* x     = (const float*)d_in[0];
  const float* Wself = (const float*)d_in[1];
  const float* Wsect = (const float*)d_in[2];
  const float* WC    = (const float*)d_in[3];
  const float* WD    = (const float*)d_in[4];
  const float* gw    = (const float*)d_in[5];
  const float* gb    = (const float*)d_in[6];
  const float* outn  = (const float*)d_in[7];
  const float* inn   = (const float*)d_in[8];
  const int*   rows  = (const int*)d_in[9];
  const int*   cols  = (const int*)d_in[10];
  float* out = (float*)d_out;

  // ws: Hbuf bf16 40.96 | Zbuf f32 92.16 | ZCD bf16 92.16 (xb aliases its head)
  char* p = (char*)d_ws;
  unsigned short* Hbuf = (unsigned short*)p; p += (size_t)S_SECT*N_NODES*OUT_DIM*2;
  float* Zbuf = (float*)p;                   p += (size_t)M_ROWS*OUT_DIM*4;
  unsigned short* ZCD = (unsigned short*)p;  p += (size_t)2*N_NODES*NK*2;
  int* cnt    = (int*)p;                     p += (size_t)N_BINS*4;
  int* offs   = (int*)p;                     p += (size_t)N_BINS*4;
  int* cur    = (int*)p;                     p += (size_t)N_BINS*4;
  int* bsum   = (int*)p;                     p += 256*4;
  int* boff   = (int*)p;                     p += 256*4;
  int* eCol   = (int*)p;                     p += (size_t)N_EDGES*4;
  unsigned short* Btg = (unsigned short*)p;  p += 256*128*2;
  unsigned short* Wtg = (unsigned short*)p;  p += (size_t)NK*IN_DIM*2;
  // xb (10.26 MB) aliases ZCD head: xb's last read (k_gemm_xw_mfma) precedes
  // ZCD's first write (k_gemm_zcd) in stream order.
  unsigned short* xb = ZCD;

  hipMemsetAsync(cnt, 0, (size_t)N_BINS*4, stream);
  hipMemsetAsync(cur, 0, (size_t)N_BINS*4, stream);

  k_prep_x <<<(M_PAD*IN_DIM/4 + 255)/256, 256, 0, stream>>>(x, xb);
  k_prep_wt<<<(NK*IN_DIM + 255)/256, 256, 0, stream>>>(Wself, Wsect, Wtg);
  k_prep_bt<<<128, 256, 0, stream>>>(WC, WD, Btg);

  dim3 gA(M_PAD/64, 3);
  k_gemm_xw_mfma<<<gA, 256, 0, stream>>>(xb, Wtg, outn, inn, Hbuf, Zbuf);

  const int eb = (N_EDGES + 255)/256;
  k_count  <<<eb, 256, 0, stream>>>(rows, cnt);
  k_scan1  <<<SCAN_BLOCKS, 256, 0, stream>>>(cnt, bsum);
  k_scan2  <<<1, 64, 0, stream>>>(bsum, boff);
  k_scan3  <<<SCAN_BLOCKS, 256, 0, stream>>>(cnt, boff, offs);
  k_scatter<<<eb, 256, 0, stream>>>(rows, cols, offs, cur, eCol);

  const int aggBlocks = (N_BINS*32 + 255)/256;
  k_agg_csr<<<aggBlocks, 256, 0, stream>>>(Hbuf, offs, cnt, eCol, inn, Zbuf);

  k_gemm_zcd<<<(M_ROWS + 127)/128, 256, 0, stream>>>(Zbuf, Btg, ZCD);

  k_interact_lite<<<N_NODES/8, 256, 0, stream>>>(ZCD, gw, gb, out);
}

// Round 5
// 411.225 us; speedup vs baseline: 3.0491x; 1.2235x over previous
//
#include <hip/hip_runtime.h>
#include <math.h>

#define N_NODES 20000
#define IN_DIM  256
#define OUT_DIM 128
#define S_SECT  8
#define K_BR    9
#define NK      (K_BR*OUT_DIM)   // 1152
#define EP_EDGE 40000
#define N_EDGES (S_SECT*EP_EDGE) // 320000
#define N_BINS  (S_SECT*N_NODES) // 160000
#define SCAN_BLOCKS 160
#define M_ROWS  (N_NODES*K_BR)   // 180000
#define BP      264              // B LDS pitch (shorts): 528B, 16B-aligned, 2-way banks

typedef float v4f __attribute__((ext_vector_type(4)));
typedef short v8s __attribute__((ext_vector_type(8)));

__device__ inline unsigned short f2bf(float f) {
  union { float f; unsigned u; } v; v.f = f;
  unsigned r = v.u + 0x7fff + ((v.u >> 16) & 1);   // RNE
  return (unsigned short)(r >> 16);
}
__device__ inline float bf2f(unsigned short h) {
  union { unsigned u; float f; } v; v.u = ((unsigned)h) << 16;
  return v.f;
}

// prep: Wtg[j][k] = bf16(Wcat[k][j]), j = 0..1151 (self | sect0..7)
__global__ __launch_bounds__(256) void k_prep_wt(
    const float* __restrict__ Wself, const float* __restrict__ Wsect,
    unsigned short* __restrict__ Wtg)
{
  const int id = blockIdx.x * 256 + threadIdx.x;      // 294912
  if (id >= NK*IN_DIM) return;
  const int j = id >> 8, k = id & 255;
  float w;
  if (j < OUT_DIM) w = Wself[(size_t)k*OUT_DIM + j];
  else {
    const int s = (j - OUT_DIM) >> 7, c = (j - OUT_DIM) & 127;
    w = Wsect[(size_t)s*(IN_DIM*OUT_DIM) + (size_t)k*OUT_DIM + c];
  }
  Wtg[id] = f2bf(w);
}

// ---------------------------------------------------------------------------
// Kernel A (MFMA+LDS): P = x @ Wtg^T  (M=20096 tiles, K=256, N=1152)
// Block: 4 waves, tile 128x128. B panel (64 KB) staged in LDS once; A frags
// in regs (fp32->bf16 inline). N-tile==sector width -> no inner branches.
//   blockIdx.y==0 -> Zbuf[n,0,:]*inn (fp32) ; else Hbuf[y-1,n,:]*outn (bf16)
// ---------------------------------------------------------------------------
__global__ __launch_bounds__(256, 2) void k_gemm_xw_mfma(
    const float* __restrict__ x, const unsigned short* __restrict__ Wtg,
    const float* __restrict__ outn, const float* __restrict__ inn,
    unsigned short* __restrict__ Hbuf, float* __restrict__ Zbuf)
{
  __shared__ unsigned short Bls[128*BP];   // 67584 B
  const int t = threadIdx.x;
  const int wave = t >> 6, lane = t & 63;
  const int mrow = lane & 15, quad = lane >> 4;
  const int m0 = blockIdx.x * 128 + wave * 32;
  const int jbase = blockIdx.y * 128;

  // stage B panel: 128 cols x 512B = 4096 16B-chunks, 16 per thread
  #pragma unroll
  for (int i = 0; i < 16; ++i) {
    const int idx = t + i*256;
    const int col = idx >> 5, ch = idx & 31;
    *(uint4*)(Bls + col*BP + ch*8) =
        *(const uint4*)(Wtg + (size_t)(jbase + col)*IN_DIM + ch*8);
  }

  // A fragments: rows m0+rb*16+mrow, fp32->bf16
  v8s afr[2][8];
  #pragma unroll
  for (int rb = 0; rb < 2; ++rb) {
    const int r = m0 + rb*16 + mrow;
    const bool ok = (r < N_NODES);
    const float* src = x + (size_t)r*IN_DIM + quad*8;
    #pragma unroll
    for (int kq = 0; kq < 8; ++kq) {
      float4 a0 = {0.f,0.f,0.f,0.f}, a1 = {0.f,0.f,0.f,0.f};
      if (ok) {
        a0 = *(const float4*)(src + kq*32);
        a1 = *(const float4*)(src + kq*32 + 4);
      }
      v8s f;
      f[0] = (short)f2bf(a0.x); f[1] = (short)f2bf(a0.y);
      f[2] = (short)f2bf(a0.z); f[3] = (short)f2bf(a0.w);
      f[4] = (short)f2bf(a1.x); f[5] = (short)f2bf(a1.y);
      f[6] = (short)f2bf(a1.z); f[7] = (short)f2bf(a1.w);
      afr[rb][kq] = f;
    }
  }
  __syncthreads();

  v4f acc[2][8];
  #pragma unroll
  for (int rb = 0; rb < 2; ++rb)
    #pragma unroll
    for (int jt = 0; jt < 8; ++jt) acc[rb][jt] = (v4f){0.f,0.f,0.f,0.f};

  #pragma unroll
  for (int kq = 0; kq < 8; ++kq) {
    #pragma unroll
    for (int jt = 0; jt < 8; ++jt) {
      const v8s bf = *(const v8s*)(Bls + (jt*16 + mrow)*BP + kq*32 + quad*8);
      acc[0][jt] = __builtin_amdgcn_mfma_f32_16x16x32_bf16(afr[0][kq], bf, acc[0][jt], 0, 0, 0);
      acc[1][jt] = __builtin_amdgcn_mfma_f32_16x16x32_bf16(afr[1][kq], bf, acc[1][jt], 0, 0, 0);
    }
  }

  // C/D: row = m0+rb*16+quad*4+p (A), col = jbase+jt*16+mrow (B)
  if (blockIdx.y == 0) {
    #pragma unroll
    for (int rb = 0; rb < 2; ++rb)
      #pragma unroll
      for (int p = 0; p < 4; ++p) {
        const int R = m0 + rb*16 + quad*4 + p;
        if (R >= N_NODES) continue;
        const float iw = inn[R];
        #pragma unroll
        for (int jt = 0; jt < 8; ++jt)
          Zbuf[(size_t)R*NK + jt*16 + mrow] = acc[rb][jt][p] * iw;
      }
  } else {
    const int s = blockIdx.y - 1;
    #pragma unroll
    for (int rb = 0; rb < 2; ++rb)
      #pragma unroll
      for (int p = 0; p < 4; ++p) {
        const int R = m0 + rb*16 + quad*4 + p;
        if (R >= N_NODES) continue;
        const float ow = outn[R];
        #pragma unroll
        for (int jt = 0; jt < 8; ++jt)
          Hbuf[((size_t)s*N_NODES + R)*OUT_DIM + jt*16 + mrow] = f2bf(acc[rb][jt][p] * ow);
      }
  }
}

// ---------------------------------------------------------------------------
// CSR build: count -> scan(3) -> scatter
// ---------------------------------------------------------------------------
__global__ __launch_bounds__(256) void k_count(
    const int* __restrict__ rows, int* __restrict__ cnt)
{
  const int id = blockIdx.x * 256 + threadIdx.x;
  if (id >= N_EDGES) return;
  const int s = id / EP_EDGE;
  atomicAdd(&cnt[s * N_NODES + rows[id]], 1);
}

__global__ __launch_bounds__(256) void k_scan1(
    const int* __restrict__ cnt, int* __restrict__ bsum)
{
  __shared__ int sh[256];
  const int t = threadIdx.x;
  const int base = blockIdx.x * 1000;
  int s = 0;
  if (t < 250) {
    const int i = base + t*4;
    s = cnt[i] + cnt[i+1] + cnt[i+2] + cnt[i+3];
  }
  sh[t] = s; __syncthreads();
  for (int off = 128; off > 0; off >>= 1) {
    if (t < off) sh[t] += sh[t + off];
    __syncthreads();
  }
  if (t == 0) bsum[blockIdx.x] = sh[0];
}

__global__ void k_scan2(const int* __restrict__ bsum, int* __restrict__ boff)
{
  if (threadIdx.x == 0) {
    int acc = 0;
    for (int b = 0; b < SCAN_BLOCKS; ++b) { boff[b] = acc; acc += bsum[b]; }
  }
}

__global__ __launch_bounds__(256) void k_scan3(
    const int* __restrict__ cnt, const int* __restrict__ boff,
    int* __restrict__ offs)
{
  __shared__ int sh[256];
  const int t = threadIdx.x;
  const int base = blockIdx.x * 1000;
  int v[4] = {0,0,0,0};
  int mySum = 0;
  if (t < 250) {
    const int i = base + t*4;
    v[0]=cnt[i]; v[1]=cnt[i+1]; v[2]=cnt[i+2]; v[3]=cnt[i+3];
    mySum = v[0]+v[1]+v[2]+v[3];
  }
  sh[t] = mySum; __syncthreads();
  for (int off = 1; off < 256; off <<= 1) {
    int add = (t >= off) ? sh[t - off] : 0;
    __syncthreads();
    sh[t] += add;
    __syncthreads();
  }
  if (t < 250) {
    int excl = boff[blockIdx.x] + sh[t] - mySum;
    const int i = base + t*4;
    offs[i]   = excl;           excl += v[0];
    offs[i+1] = excl;           excl += v[1];
    offs[i+2] = excl;           excl += v[2];
    offs[i+3] = excl;
  }
}

__global__ __launch_bounds__(256) void k_scatter(
    const int* __restrict__ rows, const int* __restrict__ cols,
    const int* __restrict__ offs, int* __restrict__ cur,
    int* __restrict__ eCol)
{
  const int id = blockIdx.x * 256 + threadIdx.x;
  if (id >= N_EDGES) return;
  const int s = id / EP_EDGE;
  const int bin = s * N_NODES + rows[id];
  const int pos = offs[bin] + atomicAdd(&cur[bin], 1);
  eCol[pos] = cols[id];
}

// ---------------------------------------------------------------------------
// Kernel B': pull aggregation from bf16 Hbuf; fold in_norm; fp32 store.
// ---------------------------------------------------------------------------
__global__ __launch_bounds__(256) void k_agg_csr(
    const unsigned short* __restrict__ Hbuf, const int* __restrict__ offs,
    const int* __restrict__ cnt, const int* __restrict__ eCol,
    const float* __restrict__ inn, float* __restrict__ Zbuf)
{
  const long long tid = (long long)blockIdx.x * 256 + threadIdx.x;
  const int group = (int)(tid >> 5);
  if (group >= N_BINS) return;
  const int lane = (int)(tid & 31);
  const int s = group / N_NODES;
  const int r = group - s * N_NODES;
  const int start = offs[group];
  const int n = cnt[group];
  float4 acc = {0.f, 0.f, 0.f, 0.f};
  for (int i = 0; i < n; ++i) {
    const int c = eCol[start + i];
    const uint2 h = *(const uint2*)(Hbuf + ((size_t)s*N_NODES + c)*OUT_DIM + lane*4);
    acc.x += bf2f((unsigned short)h.x);
    acc.y += bf2f((unsigned short)(h.x >> 16));
    acc.z += bf2f((unsigned short)h.y);
    acc.w += bf2f((unsigned short)(h.y >> 16));
  }
  const float w = inn[r];
  acc.x *= w; acc.y *= w; acc.z *= w; acc.w *= w;
  *(float4*)(Zbuf + ((size_t)r*K_BR + 1 + s)*OUT_DIM + lane*4) = acc;
}

// ---------------------------------------------------------------------------
// Btg[n][k] = bf16([WC|WD][k][n])   (256 x 128, 64 KB)
// ---------------------------------------------------------------------------
__global__ __launch_bounds__(256) void k_prep_bt(
    const float* __restrict__ WC, const float* __restrict__ WD,
    unsigned short* __restrict__ Btg)
{
  const int id = blockIdx.x * 256 + threadIdx.x;   // 32768
  const int n = id >> 7, k = id & 127;
  const float w = (n < OUT_DIM) ? WC[k*OUT_DIM + n] : WD[k*OUT_DIM + (n - OUT_DIM)];
  Btg[id] = f2bf(w);
}

// ---------------------------------------------------------------------------
// Kernel ZCD: [zc|zd] = Zbuf[180000,128] @ Bt^T  via bf16 MFMA 16x16x32.
// ---------------------------------------------------------------------------
__global__ __launch_bounds__(256, 2) void k_gemm_zcd(
    const float* __restrict__ Zbuf, const unsigned short* __restrict__ Btg,
    unsigned short* __restrict__ ZCD)
{
  const int t = threadIdx.x;
  const int wave = t >> 6, lane = t & 63;
  const int m0 = blockIdx.x * 128 + wave * 32;
  const int mrow = lane & 15, quad = lane >> 4;

  v8s afr[2][4];
  #pragma unroll
  for (int rb = 0; rb < 2; ++rb) {
    const int r = m0 + rb*16 + mrow;
    const bool ok = (r < M_ROWS);
    const float* src = Zbuf + (size_t)r*OUT_DIM + quad*8;
    #pragma unroll
    for (int kq = 0; kq < 4; ++kq) {
      float4 a0 = {0.f,0.f,0.f,0.f}, a1 = {0.f,0.f,0.f,0.f};
      if (ok) {
        a0 = *(const float4*)(src + kq*32);
        a1 = *(const float4*)(src + kq*32 + 4);
      }
      v8s f;
      f[0] = (short)f2bf(a0.x); f[1] = (short)f2bf(a0.y);
      f[2] = (short)f2bf(a0.z); f[3] = (short)f2bf(a0.w);
      f[4] = (short)f2bf(a1.x); f[5] = (short)f2bf(a1.y);
      f[6] = (short)f2bf(a1.z); f[7] = (short)f2bf(a1.w);
      afr[rb][kq] = f;
    }
  }

  v4f acc[2][16];
  #pragma unroll
  for (int rb = 0; rb < 2; ++rb)
    #pragma unroll
    for (int j = 0; j < 16; ++j) acc[rb][j] = (v4f){0.f,0.f,0.f,0.f};

  #pragma unroll
  for (int j = 0; j < 16; ++j) {
    const unsigned short* bp = Btg + (size_t)(j*16 + mrow)*128 + quad*8;
    #pragma unroll
    for (int kq = 0; kq < 4; ++kq) {
      const v8s bf = *(const v8s*)(bp + kq*32);
      acc[0][j] = __builtin_amdgcn_mfma_f32_16x16x32_bf16(afr[0][kq], bf, acc[0][j], 0, 0, 0);
      acc[1][j] = __builtin_amdgcn_mfma_f32_16x16x32_bf16(afr[1][kq], bf, acc[1][j], 0, 0, 0);
    }
  }

  unsigned short* Zc = ZCD;
  unsigned short* Zd = ZCD + (size_t)N_NODES*NK;
  #pragma unroll
  for (int rb = 0; rb < 2; ++rb)
    #pragma unroll
    for (int p = 0; p < 4; ++p) {
      const int R = m0 + rb*16 + quad*4 + p;
      if (R >= M_ROWS) continue;
      const int node = R / 9, kk = R - node*9;
      const size_t base = (size_t)node*NK + kk*OUT_DIM;
      #pragma unroll
      for (int j = 0; j < 16; ++j) {
        const unsigned short v = f2bf(acc[rb][j][p]);
        if (j < 8) Zc[base + j*16 + mrow] = v;
        else       Zd[base + (j-8)*16 + mrow] = v;
      }
    }
}

// ---------------------------------------------------------------------------
// Kernel C': interaction from precomputed zc/zd. 8 nodes / 256 threads.
// ---------------------------------------------------------------------------
__device__ static const signed char TKd[45] =
 {0,1,1,2,2,2,3,3,3,3,4,4,4,4,4,5,5,5,5,5,5,6,6,6,6,6,6,6,7,7,7,7,7,7,7,7,8,8,8,8,8,8,8,8,8};
__device__ static const signed char TJd[45] =
 {0,0,1,0,1,2,0,1,2,3,0,1,2,3,4,0,1,2,3,4,5,0,1,2,3,4,5,6,0,1,2,3,4,5,6,7,0,1,2,3,4,5,6,7,8};

#define ZP 130

__global__ __launch_bounds__(256, 2) void k_interact_lite(
    const unsigned short* __restrict__ ZCD, const float* __restrict__ gw,
    const float* __restrict__ gb, float* __restrict__ out)
{
  __shared__ float zcd[2][8][K_BR*ZP];
  __shared__ float gs[8][2][K_BR][10];
  __shared__ float redw[2][2];
  const int t  = threadIdx.x;
  const int n0 = blockIdx.x * 8;

  for (int it = 0; it < 18; ++it) {
    const int i4  = t + it*256;
    const int mat = (i4 >= 2304) ? 1 : 0;
    const int rem4 = i4 - mat*2304;
    const int flat = rem4 * 4;
    const int node = flat / NK;
    const int r2   = flat - node*NK;
    const int k = r2 >> 7, d = r2 & 127;
    const uint2 h = *(const uint2*)(ZCD + (size_t)mat*N_NODES*NK + (size_t)(n0+node)*NK + r2);
    float* dst = &zcd[mat][node][k*ZP + d];
    ((float2*)dst)[0] = (float2){bf2f((unsigned short)h.x), bf2f((unsigned short)(h.x>>16))};
    ((float2*)dst)[1] = (float2){bf2f((unsigned short)h.y), bf2f((unsigned short)(h.y>>16))};
  }
  __syncthreads();

  for (int p = t; p < 720; p += 256) {
    const int node = p / 90;
    const int rem  = p - node*90;
    const int mat  = (rem >= 45) ? 1 : 0;
    const int pair = rem - mat*45;
    const int k = TKd[pair], j = TJd[pair];
    const float* A = &zcd[mat][node][0];
    float s = 0.f;
    #pragma unroll 4
    for (int i = 0; i < 128; ++i) s += A[k*ZP+i] * A[j*ZP+i];
    gs[node][mat][k][j] = s;
    gs[node][mat][j][k] = s;
  }
  __syncthreads();

  if (t < 144) {
    const int node = t / 18;
    const int rem  = t - node*18;
    const int mat  = (rem >= 9) ? 1 : 0;
    const int k    = rem - mat*9;
    float v[9];
    if (mat == 0) {
      #pragma unroll
      for (int j = 0; j < 9; ++j) v[j] = gs[node][0][k][j];
    } else {
      const float gkk = gs[node][1][k][k];
      #pragma unroll
      for (int j = 0; j < 9; ++j) v[j] = gkk - gs[node][1][k][j];
    }
    float m = v[0];
    #pragma unroll
    for (int j = 1; j < 9; ++j) m = fmaxf(m, v[j]);
    float sum = 0.f;
    #pragma unroll
    for (int j = 0; j < 9; ++j) { v[j] = expf(v[j] - m); sum += v[j]; }
    const float inv = 1.f / sum;
    #pragma unroll
    for (int j = 0; j < 9; ++j) gs[node][mat][k][j] = v[j] * inv;
  }
  __syncthreads();

  const int half = t >> 7;
  const int d    = t & 127;
  const int wh   = (t >> 6) & 1;
  const int lane = t & 63;
  const float gbv = gb[0];
  for (int nn = 0; nn < 4; ++nn) {
    const int node = half*4 + nn;
    float zcj[9], zdj[9];
    #pragma unroll
    for (int j = 0; j < 9; ++j) {
      zcj[j] = zcd[0][node][j*ZP + d];
      zdj[j] = zcd[1][node][j*ZP + d];
    }
    float zcomK[9], zdisK[9];
    float gp = 0.f;
    #pragma unroll
    for (int k = 0; k < 9; ++k) {
      float zc = 0.f, ad = 0.f;
      #pragma unroll
      for (int j = 0; j < 9; ++j) {
        zc += gs[node][0][k][j] * zcj[j];
        ad += gs[node][1][k][j] * zdj[j];
      }
      zcomK[k] = zc;
      zdisK[k] = zdj[k] - ad;
      gp += zc * gw[k*OUT_DIM + d] + zdisK[k] * gw[NK + k*OUT_DIM + d];
    }
    #pragma unroll
    for (int off = 32; off > 0; off >>= 1) gp += __shfl_down(gp, off, 64);
    if (lane == 0) redw[half][wh] = gp;
    __syncthreads();
    const float beta = 1.f / (1.f + expf(-(redw[half][0] + redw[half][1] + gbv)));
    #pragma unroll
    for (int k = 0; k < 9; ++k)
      out[(size_t)(n0+node)*NK + k*OUT_DIM + d] = beta*zcomK[k] + (1.f-beta)*zdisK[k];
    __syncthreads();
  }
}

// ---------------------------------------------------------------------------
extern "C" void kernel_launch(void* const* d_in, const int* in_sizes, int n_in,
                              void* d_out, int out_size, void* d_ws, size_t ws_size,
                              hipStream_t stream)
{
  const float* x     = (const float*)d_in[0];
  const float* Wself = (const float*)d_in[1];
  const float* Wsect = (const float*)d_in[2];
  const float* WC    = (const float*)d_in[3];
  const float* WD    = (const float*)d_in[4];
  const float* gw    = (const float*)d_in[5];
  const float* gb    = (const float*)d_in[6];
  const float* outn  = (const float*)d_in[7];
  const float* inn   = (const float*)d_in[8];
  const int*   rows  = (const int*)d_in[9];
  const int*   cols  = (const int*)d_in[10];
  float* out = (float*)d_out;

  // ws: Hbuf bf16 40.96 | Zbuf f32 92.16 | ZCD bf16 92.16 | CSR+W ~4.5 MB
  char* p = (char*)d_ws;
  unsigned short* Hbuf = (unsigned short*)p; p += (size_t)S_SECT*N_NODES*OUT_DIM*2;
  float* Zbuf = (float*)p;                   p += (size_t)M_ROWS*OUT_DIM*4;
  unsigned short* ZCD = (unsigned short*)p;  p += (size_t)2*N_NODES*NK*2;
  int* cnt    = (int*)p;                     p += (size_t)N_BINS*4;
  int* offs   = (int*)p;                     p += (size_t)N_BINS*4;
  int* cur    = (int*)p;                     p += (size_t)N_BINS*4;
  int* bsum   = (int*)p;                     p += 256*4;
  int* boff   = (int*)p;                     p += 256*4;
  int* eCol   = (int*)p;                     p += (size_t)N_EDGES*4;
  unsigned short* Btg = (unsigned short*)p;  p += 256*128*2;
  unsigned short* Wtg = (unsigned short*)p;  p += (size_t)NK*IN_DIM*2;

  hipMemsetAsync(cnt, 0, (size_t)N_BINS*4, stream);
  hipMemsetAsync(cur, 0, (size_t)N_BINS*4, stream);

  k_prep_wt<<<(NK*IN_DIM + 255)/256, 256, 0, stream>>>(Wself, Wsect, Wtg);
  k_prep_bt<<<128, 256, 0, stream>>>(WC, WD, Btg);

  dim3 gA((N_NODES + 127)/128, K_BR);   // 157 x 9
  k_gemm_xw_mfma<<<gA, 256, 0, stream>>>(x, Wtg, outn, inn, Hbuf, Zbuf);

  const int eb = (N_EDGES + 255)/256;
  k_count  <<<eb, 256, 0, stream>>>(rows, cnt);
  k_scan1  <<<SCAN_BLOCKS, 256, 0, stream>>>(cnt, bsum);
  k_scan2  <<<1, 64, 0, stream>>>(bsum, boff);
  k_scan3  <<<SCAN_BLOCKS, 256, 0, stream>>>(cnt, boff, offs);
  k_scatter<<<eb, 256, 0, stream>>>(rows, cols, offs, cur, eCol);

  const int aggBlocks = (N_BINS*32 + 255)/256;
  k_agg_csr<<<aggBlocks, 256, 0, stream>>>(Hbuf, offs, cnt, eCol, inn, Zbuf);

  k_gemm_zcd<<<(M_ROWS + 127)/128, 256, 0, stream>>>(Zbuf, Btg, ZCD);

  k_interact_lite<<<N_NODES/8, 256, 0, stream>>>(ZCD, gw, gb, out);
}

// Round 6
// 370.681 us; speedup vs baseline: 3.3826x; 1.1094x over previous
//
#include <hip/hip_runtime.h>
#include <math.h>

#define N_NODES 20000
#define IN_DIM  256
#define OUT_DIM 128
#define S_SECT  8
#define K_BR    9
#define NK      (K_BR*OUT_DIM)   // 1152
#define EP_EDGE 40000
#define N_EDGES (S_SECT*EP_EDGE) // 320000
#define N_BINS  (S_SECT*N_NODES) // 160000
#define SCAN_BLOCKS 160
#define M_ROWS  (N_NODES*K_BR)   // 180000
#define BP      264              // B LDS pitch (shorts): 528B, 16B-aligned, 2-way banks

typedef float v4f __attribute__((ext_vector_type(4)));
typedef short v8s __attribute__((ext_vector_type(8)));

__device__ inline unsigned short f2bf(float f) {
  union { float f; unsigned u; } v; v.f = f;
  unsigned r = v.u + 0x7fff + ((v.u >> 16) & 1);   // RNE
  return (unsigned short)(r >> 16);
}
__device__ inline float bf2f(unsigned short h) {
  union { unsigned u; float f; } v; v.u = ((unsigned)h) << 16;
  return v.f;
}

// prep: Wtg[j][k] = bf16(Wcat[k][j]), j = 0..1151 (self | sect0..7)
__global__ __launch_bounds__(256) void k_prep_wt(
    const float* __restrict__ Wself, const float* __restrict__ Wsect,
    unsigned short* __restrict__ Wtg)
{
  const int id = blockIdx.x * 256 + threadIdx.x;      // 294912
  if (id >= NK*IN_DIM) return;
  const int j = id >> 8, k = id & 255;
  float w;
  if (j < OUT_DIM) w = Wself[(size_t)k*OUT_DIM + j];
  else {
    const int s = (j - OUT_DIM) >> 7, c = (j - OUT_DIM) & 127;
    w = Wsect[(size_t)s*(IN_DIM*OUT_DIM) + (size_t)k*OUT_DIM + c];
  }
  Wtg[id] = f2bf(w);
}

// ---------------------------------------------------------------------------
// Kernel A (MFMA+LDS): P = x @ Wtg^T
// ---------------------------------------------------------------------------
__global__ __launch_bounds__(256, 2) void k_gemm_xw_mfma(
    const float* __restrict__ x, const unsigned short* __restrict__ Wtg,
    const float* __restrict__ outn, const float* __restrict__ inn,
    unsigned short* __restrict__ Hbuf, float* __restrict__ Zbuf)
{
  __shared__ unsigned short Bls[128*BP];   // 67584 B
  const int t = threadIdx.x;
  const int wave = t >> 6, lane = t & 63;
  const int mrow = lane & 15, quad = lane >> 4;
  const int m0 = blockIdx.x * 128 + wave * 32;
  const int jbase = blockIdx.y * 128;

  #pragma unroll
  for (int i = 0; i < 16; ++i) {
    const int idx = t + i*256;
    const int col = idx >> 5, ch = idx & 31;
    *(uint4*)(Bls + col*BP + ch*8) =
        *(const uint4*)(Wtg + (size_t)(jbase + col)*IN_DIM + ch*8);
  }

  v8s afr[2][8];
  #pragma unroll
  for (int rb = 0; rb < 2; ++rb) {
    const int r = m0 + rb*16 + mrow;
    const bool ok = (r < N_NODES);
    const float* src = x + (size_t)r*IN_DIM + quad*8;
    #pragma unroll
    for (int kq = 0; kq < 8; ++kq) {
      float4 a0 = {0.f,0.f,0.f,0.f}, a1 = {0.f,0.f,0.f,0.f};
      if (ok) {
        a0 = *(const float4*)(src + kq*32);
        a1 = *(const float4*)(src + kq*32 + 4);
      }
      v8s f;
      f[0] = (short)f2bf(a0.x); f[1] = (short)f2bf(a0.y);
      f[2] = (short)f2bf(a0.z); f[3] = (short)f2bf(a0.w);
      f[4] = (short)f2bf(a1.x); f[5] = (short)f2bf(a1.y);
      f[6] = (short)f2bf(a1.z); f[7] = (short)f2bf(a1.w);
      afr[rb][kq] = f;
    }
  }
  __syncthreads();

  v4f acc[2][8];
  #pragma unroll
  for (int rb = 0; rb < 2; ++rb)
    #pragma unroll
    for (int jt = 0; jt < 8; ++jt) acc[rb][jt] = (v4f){0.f,0.f,0.f,0.f};

  #pragma unroll
  for (int kq = 0; kq < 8; ++kq) {
    #pragma unroll
    for (int jt = 0; jt < 8; ++jt) {
      const v8s bf = *(const v8s*)(Bls + (jt*16 + mrow)*BP + kq*32 + quad*8);
      acc[0][jt] = __builtin_amdgcn_mfma_f32_16x16x32_bf16(afr[0][kq], bf, acc[0][jt], 0, 0, 0);
      acc[1][jt] = __builtin_amdgcn_mfma_f32_16x16x32_bf16(afr[1][kq], bf, acc[1][jt], 0, 0, 0);
    }
  }

  if (blockIdx.y == 0) {
    #pragma unroll
    for (int rb = 0; rb < 2; ++rb)
      #pragma unroll
      for (int p = 0; p < 4; ++p) {
        const int R = m0 + rb*16 + quad*4 + p;
        if (R >= N_NODES) continue;
        const float iw = inn[R];
        #pragma unroll
        for (int jt = 0; jt < 8; ++jt)
          Zbuf[(size_t)R*NK + jt*16 + mrow] = acc[rb][jt][p] * iw;
      }
  } else {
    const int s = blockIdx.y - 1;
    #pragma unroll
    for (int rb = 0; rb < 2; ++rb)
      #pragma unroll
      for (int p = 0; p < 4; ++p) {
        const int R = m0 + rb*16 + quad*4 + p;
        if (R >= N_NODES) continue;
        const float ow = outn[R];
        #pragma unroll
        for (int jt = 0; jt < 8; ++jt)
          Hbuf[((size_t)s*N_NODES + R)*OUT_DIM + jt*16 + mrow] = f2bf(acc[rb][jt][p] * ow);
      }
  }
}

// ---------------------------------------------------------------------------
// CSR build: count -> scan(3) -> scatter
// ---------------------------------------------------------------------------
__global__ __launch_bounds__(256) void k_count(
    const int* __restrict__ rows, int* __restrict__ cnt)
{
  const int id = blockIdx.x * 256 + threadIdx.x;
  if (id >= N_EDGES) return;
  const int s = id / EP_EDGE;
  atomicAdd(&cnt[s * N_NODES + rows[id]], 1);
}

__global__ __launch_bounds__(256) void k_scan1(
    const int* __restrict__ cnt, int* __restrict__ bsum)
{
  __shared__ int sh[256];
  const int t = threadIdx.x;
  const int base = blockIdx.x * 1000;
  int s = 0;
  if (t < 250) {
    const int i = base + t*4;
    s = cnt[i] + cnt[i+1] + cnt[i+2] + cnt[i+3];
  }
  sh[t] = s; __syncthreads();
  for (int off = 128; off > 0; off >>= 1) {
    if (t < off) sh[t] += sh[t + off];
    __syncthreads();
  }
  if (t == 0) bsum[blockIdx.x] = sh[0];
}

__global__ void k_scan2(const int* __restrict__ bsum, int* __restrict__ boff)
{
  if (threadIdx.x == 0) {
    int acc = 0;
    for (int b = 0; b < SCAN_BLOCKS; ++b) { boff[b] = acc; acc += bsum[b]; }
  }
}

__global__ __launch_bounds__(256) void k_scan3(
    const int* __restrict__ cnt, const int* __restrict__ boff,
    int* __restrict__ offs)
{
  __shared__ int sh[256];
  const int t = threadIdx.x;
  const int base = blockIdx.x * 1000;
  int v[4] = {0,0,0,0};
  int mySum = 0;
  if (t < 250) {
    const int i = base + t*4;
    v[0]=cnt[i]; v[1]=cnt[i+1]; v[2]=cnt[i+2]; v[3]=cnt[i+3];
    mySum = v[0]+v[1]+v[2]+v[3];
  }
  sh[t] = mySum; __syncthreads();
  for (int off = 1; off < 256; off <<= 1) {
    int add = (t >= off) ? sh[t - off] : 0;
    __syncthreads();
    sh[t] += add;
    __syncthreads();
  }
  if (t < 250) {
    int excl = boff[blockIdx.x] + sh[t] - mySum;
    const int i = base + t*4;
    offs[i]   = excl;           excl += v[0];
    offs[i+1] = excl;           excl += v[1];
    offs[i+2] = excl;           excl += v[2];
    offs[i+3] = excl;
  }
}

__global__ __launch_bounds__(256) void k_scatter(
    const int* __restrict__ rows, const int* __restrict__ cols,
    const int* __restrict__ offs, int* __restrict__ cur,
    int* __restrict__ eCol)
{
  const int id = blockIdx.x * 256 + threadIdx.x;
  if (id >= N_EDGES) return;
  const int s = id / EP_EDGE;
  const int bin = s * N_NODES + rows[id];
  const int pos = offs[bin] + atomicAdd(&cur[bin], 1);
  eCol[pos] = cols[id];
}

// ---------------------------------------------------------------------------
// Kernel B': pull aggregation from bf16 Hbuf; fold in_norm; fp32 store.
// ---------------------------------------------------------------------------
__global__ __launch_bounds__(256) void k_agg_csr(
    const unsigned short* __restrict__ Hbuf, const int* __restrict__ offs,
    const int* __restrict__ cnt, const int* __restrict__ eCol,
    const float* __restrict__ inn, float* __restrict__ Zbuf)
{
  const long long tid = (long long)blockIdx.x * 256 + threadIdx.x;
  const int group = (int)(tid >> 5);
  if (group >= N_BINS) return;
  const int lane = (int)(tid & 31);
  const int s = group / N_NODES;
  const int r = group - s * N_NODES;
  const int start = offs[group];
  const int n = cnt[group];
  float4 acc = {0.f, 0.f, 0.f, 0.f};
  for (int i = 0; i < n; ++i) {
    const int c = eCol[start + i];
    const uint2 h = *(const uint2*)(Hbuf + ((size_t)s*N_NODES + c)*OUT_DIM + lane*4);
    acc.x += bf2f((unsigned short)h.x);
    acc.y += bf2f((unsigned short)(h.x >> 16));
    acc.z += bf2f((unsigned short)h.y);
    acc.w += bf2f((unsigned short)(h.y >> 16));
  }
  const float w = inn[r];
  acc.x *= w; acc.y *= w; acc.z *= w; acc.w *= w;
  *(float4*)(Zbuf + ((size_t)r*K_BR + 1 + s)*OUT_DIM + lane*4) = acc;
}

// ---------------------------------------------------------------------------
// Btg[n][k] = bf16([WC|WD][k][n])   (256 x 128, 64 KB)
// ---------------------------------------------------------------------------
__global__ __launch_bounds__(256) void k_prep_bt(
    const float* __restrict__ WC, const float* __restrict__ WD,
    unsigned short* __restrict__ Btg)
{
  const int id = blockIdx.x * 256 + threadIdx.x;   // 32768
  const int n = id >> 7, k = id & 127;
  const float w = (n < OUT_DIM) ? WC[k*OUT_DIM + n] : WD[k*OUT_DIM + (n - OUT_DIM)];
  Btg[id] = f2bf(w);
}

// ---------------------------------------------------------------------------
// Kernel ZCD: [zc|zd] = Zbuf[180000,128] @ Bt^T  via bf16 MFMA 16x16x32.
// ---------------------------------------------------------------------------
__global__ __launch_bounds__(256, 2) void k_gemm_zcd(
    const float* __restrict__ Zbuf, const unsigned short* __restrict__ Btg,
    unsigned short* __restrict__ ZCD)
{
  const int t = threadIdx.x;
  const int wave = t >> 6, lane = t & 63;
  const int m0 = blockIdx.x * 128 + wave * 32;
  const int mrow = lane & 15, quad = lane >> 4;

  v8s afr[2][4];
  #pragma unroll
  for (int rb = 0; rb < 2; ++rb) {
    const int r = m0 + rb*16 + mrow;
    const bool ok = (r < M_ROWS);
    const float* src = Zbuf + (size_t)r*OUT_DIM + quad*8;
    #pragma unroll
    for (int kq = 0; kq < 4; ++kq) {
      float4 a0 = {0.f,0.f,0.f,0.f}, a1 = {0.f,0.f,0.f,0.f};
      if (ok) {
        a0 = *(const float4*)(src + kq*32);
        a1 = *(const float4*)(src + kq*32 + 4);
      }
      v8s f;
      f[0] = (short)f2bf(a0.x); f[1] = (short)f2bf(a0.y);
      f[2] = (short)f2bf(a0.z); f[3] = (short)f2bf(a0.w);
      f[4] = (short)f2bf(a1.x); f[5] = (short)f2bf(a1.y);
      f[6] = (short)f2bf(a1.z); f[7] = (short)f2bf(a1.w);
      afr[rb][kq] = f;
    }
  }

  v4f acc[2][16];
  #pragma unroll
  for (int rb = 0; rb < 2; ++rb)
    #pragma unroll
    for (int j = 0; j < 16; ++j) acc[rb][j] = (v4f){0.f,0.f,0.f,0.f};

  #pragma unroll
  for (int j = 0; j < 16; ++j) {
    const unsigned short* bp = Btg + (size_t)(j*16 + mrow)*128 + quad*8;
    #pragma unroll
    for (int kq = 0; kq < 4; ++kq) {
      const v8s bf = *(const v8s*)(bp + kq*32);
      acc[0][j] = __builtin_amdgcn_mfma_f32_16x16x32_bf16(afr[0][kq], bf, acc[0][j], 0, 0, 0);
      acc[1][j] = __builtin_amdgcn_mfma_f32_16x16x32_bf16(afr[1][kq], bf, acc[1][j], 0, 0, 0);
    }
  }

  unsigned short* Zc = ZCD;
  unsigned short* Zd = ZCD + (size_t)N_NODES*NK;
  #pragma unroll
  for (int rb = 0; rb < 2; ++rb)
    #pragma unroll
    for (int p = 0; p < 4; ++p) {
      const int R = m0 + rb*16 + quad*4 + p;
      if (R >= M_ROWS) continue;
      const int node = R / 9, kk = R - node*9;
      const size_t base = (size_t)node*NK + kk*OUT_DIM;
      #pragma unroll
      for (int j = 0; j < 16; ++j) {
        const unsigned short v = f2bf(acc[rb][j][p]);
        if (j < 8) Zc[base + j*16 + mrow] = v;
        else       Zd[base + (j-8)*16 + mrow] = v;
      }
    }
}

// ---------------------------------------------------------------------------
// k_gram: one wave per (node,mat). G = Z·Z^T via MFMA; the A-frag and B-frag
// are the SAME register (B=Z^T flips the lane mapping back onto Z rows).
// Writes the 9x9 corner to Gbuf (fp32).
// ---------------------------------------------------------------------------
__global__ __launch_bounds__(256) void k_gram(
    const unsigned short* __restrict__ ZCD, float* __restrict__ Gbuf)
{
  const int wid = (blockIdx.x * 256 + threadIdx.x) >> 6;
  if (wid >= 2*N_NODES) return;
  const int lane = threadIdx.x & 63;
  const int node = wid >> 1, mat = wid & 1;
  const int r = lane & 15, quad = lane >> 4;

  const unsigned short* src = ZCD + (size_t)mat*N_NODES*NK + (size_t)node*NK
                              + (size_t)r*OUT_DIM + quad*8;
  v8s frag[4];
  #pragma unroll
  for (int kq = 0; kq < 4; ++kq) {
    v8s f = {0,0,0,0,0,0,0,0};
    if (r < K_BR) f = *(const v8s*)(src + kq*32);
    frag[kq] = f;
  }
  v4f acc = {0.f,0.f,0.f,0.f};
  #pragma unroll
  for (int kq = 0; kq < 4; ++kq)
    acc = __builtin_amdgcn_mfma_f32_16x16x32_bf16(frag[kq], frag[kq], acc, 0, 0, 0);

  // D: col n = lane&15, row m = quad*4+p
  const int n = lane & 15;
  if (n < K_BR) {
    float* g = Gbuf + ((size_t)node*2 + mat)*81;
    #pragma unroll
    for (int p = 0; p < 4; ++p) {
      const int m = quad*4 + p;
      if (m < K_BR) g[m*9 + n] = acc[p];
    }
  }
}

// ---------------------------------------------------------------------------
// k_interact2: softmax(Gbuf) + combine + gate. 8 nodes / 256 threads.
// zc/zd read directly from global ZCD (coalesced bf16). LDS = 5.8 KB.
// ---------------------------------------------------------------------------
__global__ __launch_bounds__(256) void k_interact2(
    const unsigned short* __restrict__ ZCD, const float* __restrict__ Gbuf,
    const float* __restrict__ gw, const float* __restrict__ gb,
    float* __restrict__ out)
{
  __shared__ float gs[8][2][K_BR][10];
  __shared__ float redw[2][2];
  const int t  = threadIdx.x;
  const int n0 = blockIdx.x * 8;

  if (t < 144) {
    const int node = t / 18;
    const int rem  = t - node*18;
    const int mat  = (rem >= 9) ? 1 : 0;
    const int k    = rem - mat*9;
    const float* g = Gbuf + ((size_t)(n0+node)*2 + mat)*81 + k*9;
    float v[9];
    if (mat == 0) {
      #pragma unroll
      for (int j = 0; j < 9; ++j) v[j] = g[j];
    } else {
      const float gkk = g[k];
      #pragma unroll
      for (int j = 0; j < 9; ++j) v[j] = gkk - g[j];
    }
    float m = v[0];
    #pragma unroll
    for (int j = 1; j < 9; ++j) m = fmaxf(m, v[j]);
    float sum = 0.f;
    #pragma unroll
    for (int j = 0; j < 9; ++j) { v[j] = expf(v[j] - m); sum += v[j]; }
    const float inv = 1.f / sum;
    #pragma unroll
    for (int j = 0; j < 9; ++j) gs[node][mat][k][j] = v[j] * inv;
  }
  __syncthreads();

  const int half = t >> 7;
  const int d    = t & 127;
  const int wh   = (t >> 6) & 1;
  const int lane = t & 63;
  const float gbv = gb[0];
  float gwc[9], gwd[9];
  #pragma unroll
  for (int j = 0; j < 9; ++j) {
    gwc[j] = gw[j*OUT_DIM + d];
    gwd[j] = gw[NK + j*OUT_DIM + d];
  }

  for (int nn = 0; nn < 4; ++nn) {
    const int node = half*4 + nn;
    const unsigned short* zcp = ZCD + (size_t)(n0+node)*NK + d;
    const unsigned short* zdp = zcp + (size_t)N_NODES*NK;
    float zcj[9], zdj[9];
    #pragma unroll
    for (int j = 0; j < 9; ++j) {
      zcj[j] = bf2f(zcp[j*OUT_DIM]);
      zdj[j] = bf2f(zdp[j*OUT_DIM]);
    }
    float zcomK[9], zdisK[9];
    float gp = 0.f;
    #pragma unroll
    for (int k = 0; k < 9; ++k) {
      float zc = 0.f, ad = 0.f;
      #pragma unroll
      for (int j = 0; j < 9; ++j) {
        zc += gs[node][0][k][j] * zcj[j];
        ad += gs[node][1][k][j] * zdj[j];
      }
      zcomK[k] = zc;
      zdisK[k] = zdj[k] - ad;
      gp += zc * gwc[k] + zdisK[k] * gwd[k];
    }
    #pragma unroll
    for (int off = 32; off > 0; off >>= 1) gp += __shfl_down(gp, off, 64);
    if (lane == 0) redw[half][wh] = gp;
    __syncthreads();
    const float beta = 1.f / (1.f + expf(-(redw[half][0] + redw[half][1] + gbv)));
    #pragma unroll
    for (int k = 0; k < 9; ++k)
      out[(size_t)(n0+node)*NK + k*OUT_DIM + d] = beta*zcomK[k] + (1.f-beta)*zdisK[k];
    __syncthreads();
  }
}

// ---------------------------------------------------------------------------
extern "C" void kernel_launch(void* const* d_in, const int* in_sizes, int n_in,
                              void* d_out, int out_size, void* d_ws, size_t ws_size,
                              hipStream_t stream)
{
  const float* x     = (const float*)d_in[0];
  const float* Wself = (const float*)d_in[1];
  const float* Wsect = (const float*)d_in[2];
  const float* WC    = (const float*)d_in[3];
  const float* WD    = (const float*)d_in[4];
  const float* gw    = (const float*)d_in[5];
  const float* gb    = (const float*)d_in[6];
  const float* outn  = (const float*)d_in[7];
  const float* inn   = (const float*)d_in[8];
  const int*   rows  = (const int*)d_in[9];
  const int*   cols  = (const int*)d_in[10];
  float* out = (float*)d_out;

  // ws: Hbuf bf16 40.96 | Zbuf f32 92.16 | ZCD bf16 92.16 | CSR+W ~4.5 MB
  // Gbuf (12.96 MB) aliases Hbuf: Hbuf's last read (k_agg_csr) precedes
  // k_gram's first write in stream order.
  char* p = (char*)d_ws;
  unsigned short* Hbuf = (unsigned short*)p; p += (size_t)S_SECT*N_NODES*OUT_DIM*2;
  float* Zbuf = (float*)p;                   p += (size_t)M_ROWS*OUT_DIM*4;
  unsigned short* ZCD = (unsigned short*)p;  p += (size_t)2*N_NODES*NK*2;
  int* cnt    = (int*)p;                     p += (size_t)N_BINS*4;
  int* offs   = (int*)p;                     p += (size_t)N_BINS*4;
  int* cur    = (int*)p;                     p += (size_t)N_BINS*4;
  int* bsum   = (int*)p;                     p += 256*4;
  int* boff   = (int*)p;                     p += 256*4;
  int* eCol   = (int*)p;                     p += (size_t)N_EDGES*4;
  unsigned short* Btg = (unsigned short*)p;  p += 256*128*2;
  unsigned short* Wtg = (unsigned short*)p;  p += (size_t)NK*IN_DIM*2;
  float* Gbuf = (float*)Hbuf;

  hipMemsetAsync(cnt, 0, (size_t)N_BINS*4, stream);
  hipMemsetAsync(cur, 0, (size_t)N_BINS*4, stream);

  k_prep_wt<<<(NK*IN_DIM + 255)/256, 256, 0, stream>>>(Wself, Wsect, Wtg);
  k_prep_bt<<<128, 256, 0, stream>>>(WC, WD, Btg);

  dim3 gA((N_NODES + 127)/128, K_BR);   // 157 x 9
  k_gemm_xw_mfma<<<gA, 256, 0, stream>>>(x, Wtg, outn, inn, Hbuf, Zbuf);

  const int eb = (N_EDGES + 255)/256;
  k_count  <<<eb, 256, 0, stream>>>(rows, cnt);
  k_scan1  <<<SCAN_BLOCKS, 256, 0, stream>>>(cnt, bsum);
  k_scan2  <<<1, 64, 0, stream>>>(bsum, boff);
  k_scan3  <<<SCAN_BLOCKS, 256, 0, stream>>>(cnt, boff, offs);
  k_scatter<<<eb, 256, 0, stream>>>(rows, cols, offs, cur, eCol);

  const int aggBlocks = (N_BINS*32 + 255)/256;
  k_agg_csr<<<aggBlocks, 256, 0, stream>>>(Hbuf, offs, cnt, eCol, inn, Zbuf);

  k_gemm_zcd<<<(M_ROWS + 127)/128, 256, 0, stream>>>(Zbuf, Btg, ZCD);

  k_gram<<<(2*N_NODES)/4, 256, 0, stream>>>(ZCD, Gbuf);

  k_interact2<<<N_NODES/8, 256, 0, stream>>>(ZCD, Gbuf, gw, gb, out);
}